// Round 2
// baseline (1768.116 us; speedup 1.0000x reference)
//
#include <hip/hip_runtime.h>
#include <math.h>

#define N_NODES 10000
#define N_EDGES 100000
#define DIM 256
#define NH 4
#define CDIM 64
#define NCH 4
#define HIDD 8
#define OUTD 4

__device__ __forceinline__ float4 ldf4(const float* p) {
    return *reinterpret_cast<const float4*>(p);
}

// ---------------------------------------------------------------- degree
__global__ __launch_bounds__(256) void deg_kernel(const int* __restrict__ ei,
                                                  float* __restrict__ cnt) {
    int e = blockIdx.x * 256 + threadIdx.x;
    if (e < N_EDGES) atomicAdd(&cnt[ei[N_EDGES + e]], 1.0f);
}

// ---------------------------------------------------------------- GEMM
// out[n][j] = bias[j] + sum_i A[n][i] * W[j][i]   (A: N x 256, W: 256 x 256)
// blockIdx.z selects which of {Q,K,V,skip} this block computes.
__global__ __launch_bounds__(256) void gemm4(
    const float* __restrict__ x,
    const float* __restrict__ Wq, const float* __restrict__ bq,
    const float* __restrict__ Wk, const float* __restrict__ bk,
    const float* __restrict__ Wv, const float* __restrict__ bv,
    const float* __restrict__ Ws, const float* __restrict__ bs,
    float* __restrict__ Qo, float* __restrict__ Ko, float* __restrict__ Vo,
    float* __restrict__ XC, int c)
{
    const float* W; const float* bias; float* out; int ldC;
    if (blockIdx.z == 0)      { W = Wq + c*DIM*DIM; bias = bq + c*DIM; out = Qo;          ldC = DIM; }
    else if (blockIdx.z == 1) { W = Wk + c*DIM*DIM; bias = bk + c*DIM; out = Ko;          ldC = DIM; }
    else if (blockIdx.z == 2) { W = Wv + c*DIM*DIM; bias = bv + c*DIM; out = Vo;          ldC = DIM; }
    else                      { W = Ws + c*DIM*DIM; bias = bs + c*DIM; out = XC + c*DIM;  ldC = NCH*DIM; }

    __shared__ float As[32][68];   // [k][m], padded: row = 272B (16B aligned)
    __shared__ float Bs[32][68];   // [k][n]
    const int tid = threadIdx.x;
    const int bm = blockIdx.x * 64, bn = blockIdx.y * 64;
    const int tm = (tid >> 4) * 4, tn = (tid & 15) * 4;
    float acc[4][4] = {};

    for (int k0 = 0; k0 < DIM; k0 += 32) {
        #pragma unroll
        for (int l = 0; l < 2; ++l) {
            int idx = tid + l * 256;       // 0..511
            int r   = idx >> 3;            // 0..63
            int c4  = (idx & 7) * 4;       // 0..28
            float4 av = make_float4(0.f, 0.f, 0.f, 0.f);
            int gr = bm + r;
            if (gr < N_NODES) av = ldf4(&x[gr * DIM + k0 + c4]);
            As[c4+0][r] = av.x; As[c4+1][r] = av.y; As[c4+2][r] = av.z; As[c4+3][r] = av.w;
            float4 wv = ldf4(&W[(bn + r) * DIM + k0 + c4]);
            Bs[c4+0][r] = wv.x; Bs[c4+1][r] = wv.y; Bs[c4+2][r] = wv.z; Bs[c4+3][r] = wv.w;
        }
        __syncthreads();
        #pragma unroll
        for (int kk = 0; kk < 32; ++kk) {
            float4 a = ldf4(&As[kk][tm]);
            float4 b = ldf4(&Bs[kk][tn]);
            float avr[4] = {a.x, a.y, a.z, a.w};
            float bvr[4] = {b.x, b.y, b.z, b.w};
            #pragma unroll
            for (int i = 0; i < 4; ++i)
                #pragma unroll
                for (int j = 0; j < 4; ++j)
                    acc[i][j] += avr[i] * bvr[j];
        }
        __syncthreads();
    }
    #pragma unroll
    for (int i = 0; i < 4; ++i) {
        int gr = bm + tm + i;
        if (gr < N_NODES) {
            float4 r;
            r.x = acc[i][0] + bias[bn+tn+0];
            r.y = acc[i][1] + bias[bn+tn+1];
            r.z = acc[i][2] + bias[bn+tn+2];
            r.w = acc[i][3] + bias[bn+tn+3];
            *reinterpret_cast<float4*>(&out[gr * ldC + bn + tn]) = r;
        }
    }
}

// ---------------------------------------------------------------- per-edge attention
// one wave per edge; lane covers cols 4*lane..4*lane+3 (head = lane/16)
__global__ __launch_bounds__(256) void edge_kernel(
    const int* __restrict__ ei, const float* __restrict__ adjc,
    const float* __restrict__ Wec,
    const float* __restrict__ Q, const float* __restrict__ K, const float* __restrict__ V,
    float* __restrict__ AGG, float* __restrict__ ALPHA, int c)
{
    int e    = (blockIdx.x * 256 + threadIdx.x) >> 6;  // grid sized exactly: e < E
    int lane = threadIdx.x & 63;
    int s = ei[e], d = ei[N_EDGES + e];
    float av = adjc[e];
    int col = lane * 4;

    float4 qd = ldf4(&Q[d * DIM + col]);
    float4 ks = ldf4(&K[s * DIM + col]);
    float4 qs = ldf4(&Q[s * DIM + col]);
    float4 kd = ldf4(&K[d * DIM + col]);
    float4 vs = ldf4(&V[s * DIM + col]);
    float4 we = ldf4(&Wec[col]);
    float4 ea;
    ea.x = av * we.x; ea.y = av * we.y; ea.z = av * we.z; ea.w = av * we.w;

    float dot1 = qd.x*(ks.x+ea.x) + qd.y*(ks.y+ea.y) + qd.z*(ks.z+ea.z) + qd.w*(ks.w+ea.w);
    float dot2 = qs.x*kd.x + qs.y*kd.y + qs.z*kd.z + qs.w*kd.w;
    #pragma unroll
    for (int off = 1; off <= 8; off <<= 1) {
        dot1 += __shfl_xor(dot1, off, 64);
        dot2 += __shfl_xor(dot2, off, 64);
    }
    float a1 = tanhf(dot1 * 0.125f);
    float a2 = tanhf(dot2 * 0.125f);
    float al = 0.5f * (a1 + a2);
    al += __shfl_xor(al, 16, 64);
    al += __shfl_xor(al, 32, 64);
    if (lane == 0) ALPHA[e * NCH + c] = al * 0.25f;

    atomicAdd(&AGG[d * DIM + col + 0], vs.x * ea.x);
    atomicAdd(&AGG[d * DIM + col + 1], vs.y * ea.y);
    atomicAdd(&AGG[d * DIM + col + 2], vs.z * ea.z);
    atomicAdd(&AGG[d * DIM + col + 3], vs.w * ea.w);
}

// ---------------------------------------------------------------- agg/cnt into xcat
__global__ __launch_bounds__(256) void addagg(
    const float* __restrict__ AGG, const float* __restrict__ CNT,
    float* __restrict__ XCAT, int c)
{
    int i4 = blockIdx.x * 256 + threadIdx.x;   // over N*DIM/4, exact grid
    int n  = i4 >> 6;
    int j  = (i4 & 63) * 4;
    float inv = 1.0f / fmaxf(CNT[n], 1.0f);
    float4 a = ldf4(&AGG[n * DIM + j]);
    float* xc = &XCAT[n * (NCH*DIM) + c * DIM + j];
    float4 xv = ldf4(xc);
    xv.x += a.x * inv; xv.y += a.y * inv; xv.z += a.z * inv; xv.w += a.w * inv;
    *reinterpret_cast<float4*>(xc) = xv;
}

// ---------------------------------------------------------------- node MLP (1024->8 elu ->256 tanh)
__global__ __launch_bounds__(256) void node_final(
    const float* __restrict__ XCAT,
    const float* __restrict__ W1, const float* __restrict__ b1,
    const float* __restrict__ W2, const float* __restrict__ b2,
    float* __restrict__ out)
{
    int n    = (blockIdx.x * 256 + threadIdx.x) >> 6;  // exact grid: n < N
    int lane = threadIdx.x & 63;
    const float* xr = XCAT + n * (NCH*DIM);
    float4 xv[4];
    #pragma unroll
    for (int t = 0; t < 4; ++t) xv[t] = ldf4(&xr[t * 256 + lane * 4]);
    float h[HIDD];
    #pragma unroll
    for (int j = 0; j < HIDD; ++j) {
        const float* wr = W1 + j * (NCH*DIM);
        float p = 0.f;
        #pragma unroll
        for (int t = 0; t < 4; ++t) {
            float4 wv = ldf4(&wr[t * 256 + lane * 4]);
            p += xv[t].x*wv.x + xv[t].y*wv.y + xv[t].z*wv.z + xv[t].w*wv.w;
        }
        #pragma unroll
        for (int off = 1; off < 64; off <<= 1) p += __shfl_xor(p, off, 64);
        float z = p + b1[j];
        h[j] = z > 0.f ? z : (expf(z) - 1.f);
    }
    float rr[4];
    #pragma unroll
    for (int i = 0; i < 4; ++i) {
        int colj = lane * 4 + i;
        float z = b2[colj];
        #pragma unroll
        for (int j = 0; j < HIDD; ++j) z += h[j] * W2[colj * HIDD + j];
        rr[i] = tanhf(z);
    }
    float4 r; r.x = rr[0]; r.y = rr[1]; r.z = rr[2]; r.w = rr[3];
    *reinterpret_cast<float4*>(&out[n * DIM + lane * 4]) = r;
}

// ---------------------------------------------------------------- edge MLP (8->8->8->4)
__global__ __launch_bounds__(256) void edge_mlp(
    const float* __restrict__ ALPHA, const float* __restrict__ adj,
    const float* __restrict__ W1, const float* __restrict__ b1,
    const float* __restrict__ W2, const float* __restrict__ b2,
    const float* __restrict__ W3, const float* __restrict__ b3,
    float* __restrict__ out)
{
    int e = blockIdx.x * 256 + threadIdx.x;
    if (e >= N_EDGES) return;
    float in[8];
    #pragma unroll
    for (int c = 0; c < NCH; ++c) in[c] = ALPHA[e * NCH + c];
    #pragma unroll
    for (int c = 0; c < NCH; ++c) in[4 + c] = adj[c * N_EDGES + e];
    float h1[8], h2[8];
    #pragma unroll
    for (int j = 0; j < 8; ++j) {
        float z = b1[j];
        #pragma unroll
        for (int i = 0; i < 8; ++i) z += W1[j*8 + i] * in[i];
        h1[j] = z > 0.f ? z : (expf(z) - 1.f);
    }
    #pragma unroll
    for (int j = 0; j < 8; ++j) {
        float z = b2[j];
        #pragma unroll
        for (int i = 0; i < 8; ++i) z += W2[j*8 + i] * h1[i];
        h2[j] = z > 0.f ? z : (expf(z) - 1.f);
    }
    #pragma unroll
    for (int o = 0; o < 4; ++o) {
        float z = b3[o];
        #pragma unroll
        for (int j = 0; j < 8; ++j) z += W3[o*8 + j] * h2[j];
        out[o * N_EDGES + e] = z;
    }
}

// ---------------------------------------------------------------- launch
extern "C" void kernel_launch(void* const* d_in, const int* in_sizes, int n_in,
                              void* d_out, int out_size, void* d_ws, size_t ws_size,
                              hipStream_t stream) {
    const float* x    = (const float*)d_in[0];
    const int*   ei   = (const int*)  d_in[1];
    const float* adj  = (const float*)d_in[2];
    // d_in[3] = flags (unused by reference)
    const float* Wq   = (const float*)d_in[4];
    const float* bq   = (const float*)d_in[5];
    const float* Wk   = (const float*)d_in[6];
    const float* bk   = (const float*)d_in[7];
    const float* Wv   = (const float*)d_in[8];
    const float* bv   = (const float*)d_in[9];
    const float* We   = (const float*)d_in[10];
    const float* Wsk  = (const float*)d_in[11];
    const float* bsk  = (const float*)d_in[12];
    const float* Wmc1 = (const float*)d_in[13];
    const float* bmc1 = (const float*)d_in[14];
    const float* Wmc2 = (const float*)d_in[15];
    const float* bmc2 = (const float*)d_in[16];
    const float* Wm1  = (const float*)d_in[17];
    const float* bm1  = (const float*)d_in[18];
    const float* Wm2  = (const float*)d_in[19];
    const float* bm2  = (const float*)d_in[20];
    const float* Wm3  = (const float*)d_in[21];
    const float* bm3  = (const float*)d_in[22];

    float* ws    = (float*)d_ws;
    float* Q     = ws;                              // N*D
    float* K     = Q + N_NODES * DIM;               // N*D
    float* V     = K + N_NODES * DIM;               // N*D
    float* AGG   = V + N_NODES * DIM;               // N*D (per-channel, reused)
    float* XCAT  = AGG + N_NODES * DIM;             // N*CH*D
    float* ALPHA = XCAT + N_NODES * NCH * DIM;      // E*CH
    float* CNT   = ALPHA + N_EDGES * NCH;           // N

    float* xout   = (float*)d_out;                  // N*D
    float* mlpout = xout + N_NODES * DIM;           // OUT*E

    hipMemsetAsync(CNT, 0, N_NODES * sizeof(float), stream);
    deg_kernel<<<(N_EDGES + 255) / 256, 256, 0, stream>>>(ei, CNT);

    for (int c = 0; c < NCH; ++c) {
        hipMemsetAsync(AGG, 0, N_NODES * DIM * sizeof(float), stream);
        dim3 gg((N_NODES + 63) / 64, DIM / 64, 4);
        gemm4<<<gg, 256, 0, stream>>>(x, Wq, bq, Wk, bk, Wv, bv, Wsk, bsk,
                                      Q, K, V, XCAT, c);
        edge_kernel<<<N_EDGES / 4, 256, 0, stream>>>(ei, adj + c * N_EDGES,
                                                     We + c * DIM, Q, K, V,
                                                     AGG, ALPHA, c);
        addagg<<<N_NODES * DIM / 4 / 256, 256, 0, stream>>>(AGG, CNT, XCAT, c);
    }
    node_final<<<N_NODES / 4, 256, 0, stream>>>(XCAT, Wmc1, bmc1, Wmc2, bmc2, xout);
    edge_mlp<<<(N_EDGES + 255) / 256, 256, 0, stream>>>(ALPHA, adj, Wm1, bm1,
                                                        Wm2, bm2, Wm3, bm3, mlpout);
}

// Round 4
// 614.900 us; speedup vs baseline: 2.8755x; 2.8755x over previous
//
#include <hip/hip_runtime.h>
#include <math.h>

#define N_NODES 10000
#define N_EDGES 100000
#define DIM 256
#define NH 4
#define CDIM 64
#define NCH 4
#define HIDD 8
#define OUTD 4

__device__ __forceinline__ float4 ldf4(const float* p) {
    return *reinterpret_cast<const float4*>(p);
}

// ---------------------------------------------------------------- degree (int)
__global__ __launch_bounds__(256) void degi_kernel(const int* __restrict__ ei,
                                                   int* __restrict__ degi) {
    int e = blockIdx.x * 256 + threadIdx.x;
    if (e < N_EDGES) atomicAdd(&degi[ei[N_EDGES + e]], 1);
}

// ---------------------------------------------------------------- prefix sum (1 block)
// 256 threads x chunk 40 covers 10240 >= N_NODES
__global__ __launch_bounds__(256) void scan_kernel(const int* __restrict__ degi,
                                                   int* __restrict__ rowptr,
                                                   int* __restrict__ cursor) {
    __shared__ int part[256];
    int t = threadIdx.x;
    int base = t * 40;
    int s = 0;
    for (int i = 0; i < 40; ++i) { int idx = base + i; if (idx < N_NODES) s += degi[idx]; }
    part[t] = s;
    __syncthreads();
    for (int off = 1; off < 256; off <<= 1) {
        int v = part[t];
        int u = (t >= off) ? part[t - off] : 0;
        __syncthreads();
        part[t] = v + u;
        __syncthreads();
    }
    int run = (t == 0) ? 0 : part[t - 1];
    for (int i = 0; i < 40; ++i) {
        int idx = base + i;
        if (idx < N_NODES) { rowptr[idx] = run; cursor[idx] = run; run += degi[idx]; }
    }
    if (t == 255) rowptr[N_NODES] = N_EDGES;
}

// ---------------------------------------------------------------- CSR scatter
__global__ __launch_bounds__(256) void scatter_kernel(const int* __restrict__ ei,
                                                      int* __restrict__ cursor,
                                                      int* __restrict__ csr_eid,
                                                      int* __restrict__ csr_src) {
    int e = blockIdx.x * 256 + threadIdx.x;
    if (e < N_EDGES) {
        int d = ei[N_EDGES + e];
        int p = atomicAdd(&cursor[d], 1);
        csr_eid[p] = e;
        csr_src[p] = ei[e];
    }
}

// ---------------------------------------------------------------- GEMM
// out[n][j] = bias[j] + sum_i A[n][i] * W[j][i]   (A: N x 256, W: 256 x 256)
// blockIdx.z selects which of {Q,K,V,skip} this block computes.
__global__ __launch_bounds__(256) void gemm4(
    const float* __restrict__ x,
    const float* __restrict__ Wq, const float* __restrict__ bq,
    const float* __restrict__ Wk, const float* __restrict__ bk,
    const float* __restrict__ Wv, const float* __restrict__ bv,
    const float* __restrict__ Ws, const float* __restrict__ bs,
    float* __restrict__ Qo, float* __restrict__ Ko, float* __restrict__ Vo,
    float* __restrict__ XC, int c)
{
    const float* W; const float* bias; float* out; int ldC;
    if (blockIdx.z == 0)      { W = Wq + c*DIM*DIM; bias = bq + c*DIM; out = Qo;          ldC = DIM; }
    else if (blockIdx.z == 1) { W = Wk + c*DIM*DIM; bias = bk + c*DIM; out = Ko;          ldC = DIM; }
    else if (blockIdx.z == 2) { W = Wv + c*DIM*DIM; bias = bv + c*DIM; out = Vo;          ldC = DIM; }
    else                      { W = Ws + c*DIM*DIM; bias = bs + c*DIM; out = XC + c*DIM;  ldC = NCH*DIM; }

    __shared__ float As[32][68];   // [k][m]
    __shared__ float Bs[32][68];   // [k][n]
    const int tid = threadIdx.x;
    const int bm = blockIdx.x * 64, bn = blockIdx.y * 64;
    const int tm = (tid >> 4) * 4, tn = (tid & 15) * 4;
    float acc[4][4] = {};

    for (int k0 = 0; k0 < DIM; k0 += 32) {
        #pragma unroll
        for (int l = 0; l < 2; ++l) {
            int idx = tid + l * 256;       // 0..511
            int r   = idx >> 3;            // 0..63
            int c4  = (idx & 7) * 4;       // 0..28
            float4 av = make_float4(0.f, 0.f, 0.f, 0.f);
            int gr = bm + r;
            if (gr < N_NODES) av = ldf4(&x[gr * DIM + k0 + c4]);
            As[c4+0][r] = av.x; As[c4+1][r] = av.y; As[c4+2][r] = av.z; As[c4+3][r] = av.w;
            float4 wv = ldf4(&W[(bn + r) * DIM + k0 + c4]);
            Bs[c4+0][r] = wv.x; Bs[c4+1][r] = wv.y; Bs[c4+2][r] = wv.z; Bs[c4+3][r] = wv.w;
        }
        __syncthreads();
        #pragma unroll
        for (int kk = 0; kk < 32; ++kk) {
            float4 a = ldf4(&As[kk][tm]);
            float4 b = ldf4(&Bs[kk][tn]);
            float avr[4] = {a.x, a.y, a.z, a.w};
            float bvr[4] = {b.x, b.y, b.z, b.w};
            #pragma unroll
            for (int i = 0; i < 4; ++i)
                #pragma unroll
                for (int j = 0; j < 4; ++j)
                    acc[i][j] += avr[i] * bvr[j];
        }
        __syncthreads();
    }
    #pragma unroll
    for (int i = 0; i < 4; ++i) {
        int gr = bm + tm + i;
        if (gr < N_NODES) {
            float4 r;
            r.x = acc[i][0] + bias[bn+tn+0];
            r.y = acc[i][1] + bias[bn+tn+1];
            r.z = acc[i][2] + bias[bn+tn+2];
            r.w = acc[i][3] + bias[bn+tn+3];
            *reinterpret_cast<float4*>(&out[gr * ldC + bn + tn]) = r;
        }
    }
}

// ---------------------------------------------------------------- CSR edge pass
// one wave per dst node: q[dst],k[dst] resident in regs, register message acc,
// single coalesced XCAT += (agg/cnt) write. No float atomics.
__global__ __launch_bounds__(256) void edge_csr(
    const int* __restrict__ rowptr, const int* __restrict__ csr_eid,
    const int* __restrict__ csr_src,
    const float* __restrict__ adjc, const float* __restrict__ Wec,
    const float* __restrict__ Q, const float* __restrict__ K, const float* __restrict__ V,
    float* __restrict__ XCAT, float* __restrict__ ALPHA, int c)
{
    int n    = (blockIdx.x * 256 + threadIdx.x) >> 6;  // exact grid: n < N_NODES
    int lane = threadIdx.x & 63;
    int col  = lane * 4;

    float4 qd = ldf4(&Q[n * DIM + col]);
    float4 kd = ldf4(&K[n * DIM + col]);
    float4 we = ldf4(&Wec[col]);
    float4 acc = make_float4(0.f, 0.f, 0.f, 0.f);

    int p0 = rowptr[n], p1 = rowptr[n + 1];
    for (int p = p0; p < p1; ++p) {
        int eid = csr_eid[p];
        int s   = csr_src[p];
        float av = adjc[eid];
        float4 ks = ldf4(&K[s * DIM + col]);
        float4 qs = ldf4(&Q[s * DIM + col]);
        float4 vs = ldf4(&V[s * DIM + col]);
        float4 ea;
        ea.x = av * we.x; ea.y = av * we.y; ea.z = av * we.z; ea.w = av * we.w;
        float kx = ks.x + ea.x, ky = ks.y + ea.y, kz = ks.z + ea.z, kw = ks.w + ea.w;
        float dot1 = qd.x*kx + qd.y*ky + qd.z*kz + qd.w*kw;
        float dot2 = qs.x*kd.x + qs.y*kd.y + qs.z*kd.z + qs.w*kd.w;
        #pragma unroll
        for (int off = 1; off <= 8; off <<= 1) {
            dot1 += __shfl_xor(dot1, off, 64);
            dot2 += __shfl_xor(dot2, off, 64);
        }
        float al = 0.5f * (tanhf(dot1 * 0.125f) + tanhf(dot2 * 0.125f));
        al += __shfl_xor(al, 16, 64);
        al += __shfl_xor(al, 32, 64);
        if (lane == 0) ALPHA[eid * NCH + c] = al * 0.25f;
        acc.x += vs.x * ea.x; acc.y += vs.y * ea.y;
        acc.z += vs.z * ea.z; acc.w += vs.w * ea.w;
    }
    float inv = 1.0f / fmaxf((float)(p1 - p0), 1.0f);
    float* xc = &XCAT[(size_t)n * (NCH*DIM) + c * DIM + col];
    float4 xv = ldf4(xc);
    xv.x += acc.x * inv; xv.y += acc.y * inv;
    xv.z += acc.z * inv; xv.w += acc.w * inv;
    *reinterpret_cast<float4*>(xc) = xv;
}

// ---------------------------------------------------------------- node MLP (1024->8 elu ->256 tanh)
__global__ __launch_bounds__(256) void node_final(
    const float* __restrict__ XCAT,
    const float* __restrict__ W1, const float* __restrict__ b1,
    const float* __restrict__ W2, const float* __restrict__ b2,
    float* __restrict__ out)
{
    int n    = (blockIdx.x * 256 + threadIdx.x) >> 6;  // exact grid: n < N
    int lane = threadIdx.x & 63;
    const float* xr = XCAT + (size_t)n * (NCH*DIM);
    float4 xv[4];
    #pragma unroll
    for (int t = 0; t < 4; ++t) xv[t] = ldf4(&xr[t * 256 + lane * 4]);
    float h[HIDD];
    #pragma unroll
    for (int j = 0; j < HIDD; ++j) {
        const float* wr = W1 + j * (NCH*DIM);
        float p = 0.f;
        #pragma unroll
        for (int t = 0; t < 4; ++t) {
            float4 wv = ldf4(&wr[t * 256 + lane * 4]);
            p += xv[t].x*wv.x + xv[t].y*wv.y + xv[t].z*wv.z + xv[t].w*wv.w;
        }
        #pragma unroll
        for (int off = 1; off < 64; off <<= 1) p += __shfl_xor(p, off, 64);
        float z = p + b1[j];
        h[j] = z > 0.f ? z : (expf(z) - 1.f);
    }
    float rr[4];
    #pragma unroll
    for (int i = 0; i < 4; ++i) {
        int colj = lane * 4 + i;
        float z = b2[colj];
        #pragma unroll
        for (int j = 0; j < HIDD; ++j) z += h[j] * W2[colj * HIDD + j];
        rr[i] = tanhf(z);
    }
    float4 r; r.x = rr[0]; r.y = rr[1]; r.z = rr[2]; r.w = rr[3];
    *reinterpret_cast<float4*>(&out[n * DIM + lane * 4]) = r;
}

// ---------------------------------------------------------------- edge MLP (8->8->8->4)
__global__ __launch_bounds__(256) void edge_mlp(
    const float* __restrict__ ALPHA, const float* __restrict__ adj,
    const float* __restrict__ W1, const float* __restrict__ b1,
    const float* __restrict__ W2, const float* __restrict__ b2,
    const float* __restrict__ W3, const float* __restrict__ b3,
    float* __restrict__ out)
{
    int e = blockIdx.x * 256 + threadIdx.x;
    if (e >= N_EDGES) return;
    float in[8];
    #pragma unroll
    for (int c = 0; c < NCH; ++c) in[c] = ALPHA[e * NCH + c];
    #pragma unroll
    for (int c = 0; c < NCH; ++c) in[4 + c] = adj[c * N_EDGES + e];
    float h1[8], h2[8];
    #pragma unroll
    for (int j = 0; j < 8; ++j) {
        float z = b1[j];
        #pragma unroll
        for (int i = 0; i < 8; ++i) z += W1[j*8 + i] * in[i];
        h1[j] = z > 0.f ? z : (expf(z) - 1.f);
    }
    #pragma unroll
    for (int j = 0; j < 8; ++j) {
        float z = b2[j];
        #pragma unroll
        for (int i = 0; i < 8; ++i) z += W2[j*8 + i] * h1[i];
        h2[j] = z > 0.f ? z : (expf(z) - 1.f);
    }
    #pragma unroll
    for (int o = 0; o < 4; ++o) {
        float z = b3[o];
        #pragma unroll
        for (int j = 0; j < 8; ++j) z += W3[o*8 + j] * h2[j];
        out[o * N_EDGES + e] = z;
    }
}

// ---------------------------------------------------------------- launch
extern "C" void kernel_launch(void* const* d_in, const int* in_sizes, int n_in,
                              void* d_out, int out_size, void* d_ws, size_t ws_size,
                              hipStream_t stream) {
    const float* x    = (const float*)d_in[0];
    const int*   ei   = (const int*)  d_in[1];
    const float* adj  = (const float*)d_in[2];
    // d_in[3] = flags (unused by reference)
    const float* Wq   = (const float*)d_in[4];
    const float* bq   = (const float*)d_in[5];
    const float* Wk   = (const float*)d_in[6];
    const float* bk   = (const float*)d_in[7];
    const float* Wv   = (const float*)d_in[8];
    const float* bv   = (const float*)d_in[9];
    const float* We   = (const float*)d_in[10];
    const float* Wsk  = (const float*)d_in[11];
    const float* bsk  = (const float*)d_in[12];
    const float* Wmc1 = (const float*)d_in[13];
    const float* bmc1 = (const float*)d_in[14];
    const float* Wmc2 = (const float*)d_in[15];
    const float* bmc2 = (const float*)d_in[16];
    const float* Wm1  = (const float*)d_in[17];
    const float* bm1  = (const float*)d_in[18];
    const float* Wm2  = (const float*)d_in[19];
    const float* bm2  = (const float*)d_in[20];
    const float* Wm3  = (const float*)d_in[21];
    const float* bm3  = (const float*)d_in[22];

    float* ws    = (float*)d_ws;
    float* Q     = ws;                              // N*D
    float* K     = Q + N_NODES * DIM;               // N*D
    float* V     = K + N_NODES * DIM;               // N*D
    float* XCAT  = V + N_NODES * DIM;               // N*CH*D
    float* ALPHA = XCAT + (size_t)N_NODES * NCH * DIM;  // E*CH
    int*   degi    = (int*)(ALPHA + N_EDGES * NCH); // N
    int*   rowptr  = degi + N_NODES;                // N+1
    int*   cursor  = rowptr + N_NODES + 1;          // N
    int*   csr_eid = cursor + N_NODES;              // E
    int*   csr_src = csr_eid + N_EDGES;             // E

    float* xout   = (float*)d_out;                  // N*D
    float* mlpout = xout + N_NODES * DIM;           // OUT*E

    // ---- CSR build
    hipMemsetAsync(degi, 0, N_NODES * sizeof(int), stream);
    degi_kernel<<<(N_EDGES + 255) / 256, 256, 0, stream>>>(ei, degi);
    scan_kernel<<<1, 256, 0, stream>>>(degi, rowptr, cursor);
    scatter_kernel<<<(N_EDGES + 255) / 256, 256, 0, stream>>>(ei, cursor, csr_eid, csr_src);

    // ---- per-channel: 4 GEMMs then CSR edge pass
    for (int c = 0; c < NCH; ++c) {
        dim3 gg((N_NODES + 63) / 64, DIM / 64, 4);
        gemm4<<<gg, 256, 0, stream>>>(x, Wq, bq, Wk, bk, Wv, bv, Wsk, bsk,
                                      Q, K, V, XCAT, c);
        edge_csr<<<N_NODES / 4, 256, 0, stream>>>(rowptr, csr_eid, csr_src,
                                                  adj + c * N_EDGES, We + c * DIM,
                                                  Q, K, V, XCAT, ALPHA, c);
    }
    node_final<<<N_NODES / 4, 256, 0, stream>>>(XCAT, Wmc1, bmc1, Wmc2, bmc2, xout);
    edge_mlp<<<(N_EDGES + 255) / 256, 256, 0, stream>>>(ALPHA, adj, Wm1, bm1,
                                                        Wm2, bm2, Wm3, bm3, mlpout);
}

// Round 6
// 323.591 us; speedup vs baseline: 5.4640x; 1.9002x over previous
//
#include <hip/hip_runtime.h>
#include <math.h>

#define N_NODES 10000
#define N_EDGES 100000
#define DIM 256
#define NCH 4
#define HIDD 8
#define OUTD 4

typedef short s8v __attribute__((ext_vector_type(8)));   // 8 bf16 in 4 VGPRs
typedef float f4v __attribute__((ext_vector_type(4)));   // MFMA accumulator

__device__ __forceinline__ float4 ldf4(const float* p) {
    return *reinterpret_cast<const float4*>(p);
}
__device__ __forceinline__ unsigned short f2bf(float f) {  // RNE f32->bf16
    unsigned int u = __float_as_uint(f);
    u += 0x7FFFu + ((u >> 16) & 1u);
    return (unsigned short)(u >> 16);
}
__device__ __forceinline__ float bf2f(unsigned short b) {
    return __uint_as_float(((unsigned int)b) << 16);
}
__device__ __forceinline__ float4 ldbf4(const unsigned short* p) {
    ushort4 u = *reinterpret_cast<const ushort4*>(p);
    float4 f;
    f.x = bf2f(u.x); f.y = bf2f(u.y); f.z = bf2f(u.z); f.w = bf2f(u.w);
    return f;
}

// ---------------------------------------------------------------- f32 -> bf16
__global__ __launch_bounds__(256) void cvt_bf16(const float* __restrict__ src,
                                                unsigned short* __restrict__ dst, int n8) {
    int i = blockIdx.x * 256 + threadIdx.x;
    if (i >= n8) return;
    float4 v0 = ldf4(src + (size_t)i * 8);
    float4 v1 = ldf4(src + (size_t)i * 8 + 4);
    ushort4 o0, o1;
    o0.x = f2bf(v0.x); o0.y = f2bf(v0.y); o0.z = f2bf(v0.z); o0.w = f2bf(v0.w);
    o1.x = f2bf(v1.x); o1.y = f2bf(v1.y); o1.z = f2bf(v1.z); o1.w = f2bf(v1.w);
    *reinterpret_cast<ushort4*>(dst + (size_t)i * 8) = o0;
    *reinterpret_cast<ushort4*>(dst + (size_t)i * 8 + 4) = o1;
}

// ---------------------------------------------------------------- degree (int)
__global__ __launch_bounds__(256) void degi_kernel(const int* __restrict__ ei,
                                                   int* __restrict__ degi) {
    int e = blockIdx.x * 256 + threadIdx.x;
    if (e < N_EDGES) atomicAdd(&degi[ei[N_EDGES + e]], 1);
}

// ---------------------------------------------------------------- prefix sum (1 block)
__global__ __launch_bounds__(256) void scan_kernel(const int* __restrict__ degi,
                                                   int* __restrict__ rowptr,
                                                   int* __restrict__ cursor) {
    __shared__ int part[256];
    int t = threadIdx.x;
    int base = t * 40;
    int s = 0;
    for (int i = 0; i < 40; ++i) { int idx = base + i; if (idx < N_NODES) s += degi[idx]; }
    part[t] = s;
    __syncthreads();
    for (int off = 1; off < 256; off <<= 1) {
        int v = part[t];
        int u = (t >= off) ? part[t - off] : 0;
        __syncthreads();
        part[t] = v + u;
        __syncthreads();
    }
    int run = (t == 0) ? 0 : part[t - 1];
    for (int i = 0; i < 40; ++i) {
        int idx = base + i;
        if (idx < N_NODES) { rowptr[idx] = run; cursor[idx] = run; run += degi[idx]; }
    }
    if (t == 255) rowptr[N_NODES] = N_EDGES;
}

// ---------------------------------------------------------------- CSR scatter
__global__ __launch_bounds__(256) void scatter_kernel(const int* __restrict__ ei,
                                                      int* __restrict__ cursor,
                                                      int* __restrict__ csr_eid,
                                                      int* __restrict__ csr_src) {
    int e = blockIdx.x * 256 + threadIdx.x;
    if (e < N_EDGES) {
        int d = ei[N_EDGES + e];
        int p = atomicAdd(&cursor[d], 1);
        csr_eid[p] = e;
        csr_src[p] = ei[e];
    }
}

// ---------------------------------------------------------------- MFMA GEMM
// blockIdx.z = c*4 + mat (mat: 0=Q,1=K,2=V,3=skip). C[row][j] = sum_k x[row][k]*W[j][k] + b[j]
// 128x128 block tile, 4 waves (2x2), each wave 64x64 via 4x4 frags of 16x16x32 bf16 MFMA.
// A/B frags load straight from L2 (x_bf16 5MB, W 128KB resident) -- no LDS, no barriers.
__global__ __launch_bounds__(256) void gemm_mfma(
    const unsigned short* __restrict__ xb,
    const unsigned short* __restrict__ wqb, const unsigned short* __restrict__ wkb,
    const unsigned short* __restrict__ wvb, const unsigned short* __restrict__ wsb,
    const float* __restrict__ bq, const float* __restrict__ bk,
    const float* __restrict__ bv, const float* __restrict__ bs,
    unsigned short* __restrict__ QB, unsigned short* __restrict__ KB,
    unsigned short* __restrict__ VB, float* __restrict__ XCAT)
{
    const int z = blockIdx.z, c = z >> 2, mat = z & 3;
    const unsigned short* W; const float* bias;
    if (mat == 0)      { W = wqb; bias = bq; }
    else if (mat == 1) { W = wkb; bias = bk; }
    else if (mat == 2) { W = wvb; bias = bv; }
    else               { W = wsb; bias = bs; }
    W += (size_t)c * DIM * DIM; bias += c * DIM;

    const int tid = threadIdx.x, w = tid >> 6, lane = tid & 63;
    const int il = lane & 15, kg = lane >> 4;
    const int bm = blockIdx.x * 128 + (w >> 1) * 64;
    const int bn = blockIdx.y * 128 + (w & 1) * 64;

    const f4v zero = {0.f, 0.f, 0.f, 0.f};
    f4v acc[4][4];
    #pragma unroll
    for (int mi = 0; mi < 4; ++mi)
        #pragma unroll
        for (int ni = 0; ni < 4; ++ni) acc[mi][ni] = zero;

    const unsigned short* aptr[4];
    #pragma unroll
    for (int mi = 0; mi < 4; ++mi) {
        int r = bm + mi * 16 + il;
        int rc = r < N_NODES ? r : N_NODES - 1;       // clamp: loads stay in-bounds
        aptr[mi] = xb + (size_t)rc * DIM + kg * 8;
    }
    const unsigned short* bptr[4];
    #pragma unroll
    for (int ni = 0; ni < 4; ++ni) {
        int j = bn + ni * 16 + il;
        bptr[ni] = W + (size_t)j * DIM + kg * 8;
    }

    #pragma unroll 2
    for (int k0 = 0; k0 < DIM; k0 += 32) {
        s8v a[4], b[4];
        #pragma unroll
        for (int mi = 0; mi < 4; ++mi) a[mi] = *reinterpret_cast<const s8v*>(aptr[mi] + k0);
        #pragma unroll
        for (int ni = 0; ni < 4; ++ni) b[ni] = *reinterpret_cast<const s8v*>(bptr[ni] + k0);
        #pragma unroll
        for (int mi = 0; mi < 4; ++mi)
            #pragma unroll
            for (int ni = 0; ni < 4; ++ni)
                acc[mi][ni] = __builtin_amdgcn_mfma_f32_16x16x32_bf16(a[mi], b[ni], acc[mi][ni], 0, 0, 0);
    }

    // Epilogue. D layout: col = lane&15, row(local) = (lane>>4)*4 + rr  [guide §3, m89/m91]
    unsigned short* O = (mat == 0) ? QB : (mat == 1) ? KB : VB;
    #pragma unroll
    for (int ni = 0; ni < 4; ++ni) {
        int col = bn + ni * 16 + il;
        float bia = bias[col];
        #pragma unroll
        for (int mi = 0; mi < 4; ++mi) {
            #pragma unroll
            for (int rr = 0; rr < 4; ++rr) {
                int row = bm + mi * 16 + kg * 4 + rr;
                if (row < N_NODES) {
                    float v = acc[mi][ni][rr] + bia;
                    if (mat == 3) XCAT[(size_t)row * (NCH * DIM) + c * DIM + col] = v;
                    else          O[((size_t)c * N_NODES + row) * DIM + col] = f2bf(v);
                }
            }
        }
    }
}

// ---------------------------------------------------------------- fused CSR edge pass
// block = one dst node, wave = one channel. bf16 Q/K/V gathers (8B/lane).
// dot1 = q.k + av*(q.we) [q.we hoisted]; agg = we (.) sum(av*v) [we hoisted].
__global__ __launch_bounds__(256) void edge_fused(
    const int* __restrict__ rowptr, const int* __restrict__ csr_eid,
    const int* __restrict__ csr_src,
    const float* __restrict__ adj, const float* __restrict__ We,
    const unsigned short* __restrict__ QB, const unsigned short* __restrict__ KB,
    const unsigned short* __restrict__ VB,
    float* __restrict__ XCAT, float* __restrict__ ALPHA)
{
    const int n = blockIdx.x;
    const int c = threadIdx.x >> 6, lane = threadIdx.x & 63, col = lane * 4;

    const size_t nb = ((size_t)c * N_NODES + n) * DIM + col;
    float4 qd = ldbf4(QB + nb);
    float4 kd = ldbf4(KB + nb);
    float4 we = ldf4(&We[c * DIM + col]);

    float qdwe = qd.x * we.x + qd.y * we.y + qd.z * we.z + qd.w * we.w;
    #pragma unroll
    for (int off = 1; off <= 8; off <<= 1) qdwe += __shfl_xor(qdwe, off, 64);

    const float* adjc = adj + (size_t)c * N_EDGES;
    float4 acc = make_float4(0.f, 0.f, 0.f, 0.f);
    const int p0 = rowptr[n], p1 = rowptr[n + 1];
    for (int p = p0; p < p1; ++p) {
        int eid = csr_eid[p];
        int s   = csr_src[p];
        float av = adjc[eid];
        size_t sb = ((size_t)c * N_NODES + s) * DIM + col;
        float4 ks = ldbf4(KB + sb);
        float4 qs = ldbf4(QB + sb);
        float4 vs = ldbf4(VB + sb);
        float d1 = qd.x*ks.x + qd.y*ks.y + qd.z*ks.z + qd.w*ks.w;
        float d2 = qs.x*kd.x + qs.y*kd.y + qs.z*kd.z + qs.w*kd.w;
        #pragma unroll
        for (int off = 1; off <= 8; off <<= 1) {
            d1 += __shfl_xor(d1, off, 64);
            d2 += __shfl_xor(d2, off, 64);
        }
        d1 += av * qdwe;
        float al = 0.5f * (tanhf(d1 * 0.125f) + tanhf(d2 * 0.125f));
        al += __shfl_xor(al, 16, 64);
        al += __shfl_xor(al, 32, 64);
        if (lane == 0) ALPHA[(size_t)eid * NCH + c] = al * 0.25f;
        acc.x += av * vs.x; acc.y += av * vs.y;
        acc.z += av * vs.z; acc.w += av * vs.w;
    }
    float inv = 1.0f / fmaxf((float)(p1 - p0), 1.0f);
    float* xc = &XCAT[(size_t)n * (NCH * DIM) + c * DIM + col];
    float4 xv = ldf4(xc);
    xv.x += acc.x * we.x * inv; xv.y += acc.y * we.y * inv;
    xv.z += acc.z * we.z * inv; xv.w += acc.w * we.w * inv;
    *reinterpret_cast<float4*>(xc) = xv;
}

// ---------------------------------------------------------------- node MLP (1024->8 elu ->256 tanh)
__global__ __launch_bounds__(256) void node_final(
    const float* __restrict__ XCAT,
    const float* __restrict__ W1, const float* __restrict__ b1,
    const float* __restrict__ W2, const float* __restrict__ b2,
    float* __restrict__ out)
{
    int n    = (blockIdx.x * 256 + threadIdx.x) >> 6;
    int lane = threadIdx.x & 63;
    const float* xr = XCAT + (size_t)n * (NCH * DIM);
    float4 xv[4];
    #pragma unroll
    for (int t = 0; t < 4; ++t) xv[t] = ldf4(&xr[t * 256 + lane * 4]);
    float h[HIDD];
    #pragma unroll
    for (int j = 0; j < HIDD; ++j) {
        const float* wr = W1 + j * (NCH * DIM);
        float p = 0.f;
        #pragma unroll
        for (int t = 0; t < 4; ++t) {
            float4 wv = ldf4(&wr[t * 256 + lane * 4]);
            p += xv[t].x*wv.x + xv[t].y*wv.y + xv[t].z*wv.z + xv[t].w*wv.w;
        }
        #pragma unroll
        for (int off = 1; off < 64; off <<= 1) p += __shfl_xor(p, off, 64);
        float z = p + b1[j];
        h[j] = z > 0.f ? z : (expf(z) - 1.f);
    }
    float rr[4];
    #pragma unroll
    for (int i = 0; i < 4; ++i) {
        int colj = lane * 4 + i;
        float z = b2[colj];
        #pragma unroll
        for (int j = 0; j < HIDD; ++j) z += h[j] * W2[colj * HIDD + j];
        rr[i] = tanhf(z);
    }
    float4 r; r.x = rr[0]; r.y = rr[1]; r.z = rr[2]; r.w = rr[3];
    *reinterpret_cast<float4*>(&out[n * DIM + lane * 4]) = r;
}

// ---------------------------------------------------------------- edge MLP (8->8->8->4)
__global__ __launch_bounds__(256) void edge_mlp(
    const float* __restrict__ ALPHA, const float* __restrict__ adj,
    const float* __restrict__ W1, const float* __restrict__ b1,
    const float* __restrict__ W2, const float* __restrict__ b2,
    const float* __restrict__ W3, const float* __restrict__ b3,
    float* __restrict__ out)
{
    int e = blockIdx.x * 256 + threadIdx.x;
    if (e >= N_EDGES) return;
    float in[8];
    #pragma unroll
    for (int c = 0; c < NCH; ++c) in[c] = ALPHA[(size_t)e * NCH + c];
    #pragma unroll
    for (int c = 0; c < NCH; ++c) in[4 + c] = adj[(size_t)c * N_EDGES + e];
    float h1[8], h2[8];
    #pragma unroll
    for (int j = 0; j < 8; ++j) {
        float z = b1[j];
        #pragma unroll
        for (int i = 0; i < 8; ++i) z += W1[j*8 + i] * in[i];
        h1[j] = z > 0.f ? z : (expf(z) - 1.f);
    }
    #pragma unroll
    for (int j = 0; j < 8; ++j) {
        float z = b2[j];
        #pragma unroll
        for (int i = 0; i < 8; ++i) z += W2[j*8 + i] * h1[i];
        h2[j] = z > 0.f ? z : (expf(z) - 1.f);
    }
    #pragma unroll
    for (int o = 0; o < 4; ++o) {
        float z = b3[o];
        #pragma unroll
        for (int j = 0; j < 8; ++j) z += W3[o*8 + j] * h2[j];
        out[(size_t)o * N_EDGES + e] = z;
    }
}

// ---------------------------------------------------------------- launch
extern "C" void kernel_launch(void* const* d_in, const int* in_sizes, int n_in,
                              void* d_out, int out_size, void* d_ws, size_t ws_size,
                              hipStream_t stream) {
    const float* x    = (const float*)d_in[0];
    const int*   ei   = (const int*)  d_in[1];
    const float* adj  = (const float*)d_in[2];
    const float* Wq   = (const float*)d_in[4];
    const float* bq   = (const float*)d_in[5];
    const float* Wk   = (const float*)d_in[6];
    const float* bk   = (const float*)d_in[7];
    const float* Wv   = (const float*)d_in[8];
    const float* bv   = (const float*)d_in[9];
    const float* We   = (const float*)d_in[10];
    const float* Wsk  = (const float*)d_in[11];
    const float* bsk  = (const float*)d_in[12];
    const float* Wmc1 = (const float*)d_in[13];
    const float* bmc1 = (const float*)d_in[14];
    const float* Wmc2 = (const float*)d_in[15];
    const float* bmc2 = (const float*)d_in[16];
    const float* Wm1  = (const float*)d_in[17];
    const float* bm1  = (const float*)d_in[18];
    const float* Wm2  = (const float*)d_in[19];
    const float* bm2  = (const float*)d_in[20];
    const float* Wm3  = (const float*)d_in[21];
    const float* bm3  = (const float*)d_in[22];

    // ---- workspace layout (~112.2 MB total)
    char* w = (char*)d_ws;
    unsigned short* xb  = (unsigned short*)w; w += (size_t)N_NODES * DIM * 2;        // 5.12 MB
    unsigned short* wqb = (unsigned short*)w; w += (size_t)NCH * DIM * DIM * 2;      // 0.52 MB
    unsigned short* wkb = (unsigned short*)w; w += (size_t)NCH * DIM * DIM * 2;
    unsigned short* wvb = (unsigned short*)w; w += (size_t)NCH * DIM * DIM * 2;
    unsigned short* wsb = (unsigned short*)w; w += (size_t)NCH * DIM * DIM * 2;
    unsigned short* QB  = (unsigned short*)w; w += (size_t)NCH * N_NODES * DIM * 2;  // 20.48 MB
    unsigned short* KB  = (unsigned short*)w; w += (size_t)NCH * N_NODES * DIM * 2;
    unsigned short* VB  = (unsigned short*)w; w += (size_t)NCH * N_NODES * DIM * 2;
    float* XCAT  = (float*)w; w += (size_t)N_NODES * NCH * DIM * 4;                  // 40.96 MB
    float* ALPHA = (float*)w; w += (size_t)N_EDGES * NCH * 4;                        // 1.60 MB
    int* degi    = (int*)w; w += N_NODES * 4;
    int* rowptr  = (int*)w; w += (N_NODES + 1) * 4;
    int* cursor  = (int*)w; w += N_NODES * 4;
    int* csr_eid = (int*)w; w += N_EDGES * 4;
    int* csr_src = (int*)w; w += N_EDGES * 4;

    float* xout   = (float*)d_out;
    float* mlpout = xout + (size_t)N_NODES * DIM;

    // ---- bf16 conversions (x + 4 weight stacks)
    cvt_bf16<<<(N_NODES * DIM / 8 + 255) / 256, 256, 0, stream>>>(x,   xb,  N_NODES * DIM / 8);
    cvt_bf16<<<(NCH * DIM * DIM / 8 + 255) / 256, 256, 0, stream>>>(Wq,  wqb, NCH * DIM * DIM / 8);
    cvt_bf16<<<(NCH * DIM * DIM / 8 + 255) / 256, 256, 0, stream>>>(Wk,  wkb, NCH * DIM * DIM / 8);
    cvt_bf16<<<(NCH * DIM * DIM / 8 + 255) / 256, 256, 0, stream>>>(Wv,  wvb, NCH * DIM * DIM / 8);
    cvt_bf16<<<(NCH * DIM * DIM / 8 + 255) / 256, 256, 0, stream>>>(Wsk, wsb, NCH * DIM * DIM / 8);

    // ---- CSR build
    hipMemsetAsync(degi, 0, N_NODES * sizeof(int), stream);
    degi_kernel<<<(N_EDGES + 255) / 256, 256, 0, stream>>>(ei, degi);
    scan_kernel<<<1, 256, 0, stream>>>(degi, rowptr, cursor);
    scatter_kernel<<<(N_EDGES + 255) / 256, 256, 0, stream>>>(ei, cursor, csr_eid, csr_src);

    // ---- all 16 GEMMs in one dispatch
    dim3 gg((N_NODES + 127) / 128, DIM / 128, NCH * 4);
    gemm_mfma<<<gg, 256, 0, stream>>>(xb, wqb, wkb, wvb, wsb, bq, bk, bv, bsk,
                                      QB, KB, VB, XCAT);

    // ---- fused edge pass: all channels, one launch
    edge_fused<<<N_NODES, 256, 0, stream>>>(rowptr, csr_eid, csr_src, adj, We,
                                            QB, KB, VB, XCAT, ALPHA);

    node_final<<<N_NODES / 4, 256, 0, stream>>>(XCAT, Wmc1, bmc1, Wmc2, bmc2, xout);
    edge_mlp<<<(N_EDGES + 255) / 256, 256, 0, stream>>>(ALPHA, adj, Wm1, bm1,
                                                        Wm2, bm2, Wm3, bm3, mlpout);
}

// Round 10
// 265.906 us; speedup vs baseline: 6.6494x; 1.2169x over previous
//
#include <hip/hip_runtime.h>
#include <math.h>

#define N_NODES 10000
#define N_EDGES 100000
#define DIM 256
#define NCH 4
#define HIDD 8
#define OUTD 4

#define BM 128
#define BN 128
#define BK 32
#define NTM 79              // ceil(10000/128)
#define NTN 32              // 4096/128
#define NWG (NTM * NTN)     // 2528, divisible by 8
#define CPX (NWG / 8)       // 316

typedef short s8v __attribute__((ext_vector_type(8)));   // 8 bf16 in 4 VGPRs
typedef float f4v __attribute__((ext_vector_type(4)));   // MFMA accumulator

__device__ __forceinline__ float4 ldf4(const float* p) {
    return *reinterpret_cast<const float4*>(p);
}
__device__ __forceinline__ unsigned short f2bf(float f) {  // RNE f32->bf16
    unsigned int u = __float_as_uint(f);
    u += 0x7FFFu + ((u >> 16) & 1u);
    return (unsigned short)(u >> 16);
}
__device__ __forceinline__ float bf2f(unsigned short b) {
    return __uint_as_float(((unsigned int)b) << 16);
}
__device__ __forceinline__ float4 ldbf4(const unsigned short* p) {
    ushort4 u = *reinterpret_cast<const ushort4*>(p);
    float4 f;
    f.x = bf2f(u.x); f.y = bf2f(u.y); f.z = bf2f(u.z); f.w = bf2f(u.w);
    return f;
}
// async global->LDS, 16B per lane; lds base must be wave-uniform (HW adds lane*16)
__device__ __forceinline__ void gload16(const unsigned short* g, unsigned short* l) {
    __builtin_amdgcn_global_load_lds(
        (const __attribute__((address_space(1))) unsigned int*)(const void*)g,
        (__attribute__((address_space(3))) unsigned int*)(void*)l, 16, 0, 0);
}

// ---------------------------------------------------------------- f32 -> bf16
__global__ __launch_bounds__(256) void cvt_bf16(const float* __restrict__ src,
                                                unsigned short* __restrict__ dst, int n8) {
    int i = blockIdx.x * 256 + threadIdx.x;
    if (i >= n8) return;
    float4 v0 = ldf4(src + (size_t)i * 8);
    float4 v1 = ldf4(src + (size_t)i * 8 + 4);
    ushort4 o0, o1;
    o0.x = f2bf(v0.x); o0.y = f2bf(v0.y); o0.z = f2bf(v0.z); o0.w = f2bf(v0.w);
    o1.x = f2bf(v1.x); o1.y = f2bf(v1.y); o1.z = f2bf(v1.z); o1.w = f2bf(v1.w);
    *reinterpret_cast<ushort4*>(dst + (size_t)i * 8) = o0;
    *reinterpret_cast<ushort4*>(dst + (size_t)i * 8 + 4) = o1;
}

// ---------------------------------------------------------------- pack all 16 W mats -> WALL[4096][256] bf16 (+BALL)
// J = mat*1024 + c*256 + j ; WALL[J][k] = W_mat[c][j][k]
__global__ __launch_bounds__(256) void pack_w(
    const float* __restrict__ Wq, const float* __restrict__ Wk,
    const float* __restrict__ Wv, const float* __restrict__ Ws,
    const float* __restrict__ bq, const float* __restrict__ bk,
    const float* __restrict__ bv, const float* __restrict__ bs,
    unsigned short* __restrict__ WALL, float* __restrict__ BALL)
{
    int i = blockIdx.x * 256 + threadIdx.x;       // over 4096*256/8 = 131072
    int J = i >> 5;
    int kk = (i & 31) * 8;
    int mat = J >> 10, c = (J >> 8) & 3, jj = J & 255;
    const float* W = (mat == 0) ? Wq : (mat == 1) ? Wk : (mat == 2) ? Wv : Ws;
    const float* src = W + (size_t)c * 65536 + jj * 256 + kk;
    float4 v0 = ldf4(src);
    float4 v1 = ldf4(src + 4);
    ushort4 o0, o1;
    o0.x = f2bf(v0.x); o0.y = f2bf(v0.y); o0.z = f2bf(v0.z); o0.w = f2bf(v0.w);
    o1.x = f2bf(v1.x); o1.y = f2bf(v1.y); o1.z = f2bf(v1.z); o1.w = f2bf(v1.w);
    *reinterpret_cast<ushort4*>(WALL + (size_t)J * 256 + kk) = o0;
    *reinterpret_cast<ushort4*>(WALL + (size_t)J * 256 + kk + 4) = o1;
    if (kk == 0) {
        const float* b = (mat == 0) ? bq : (mat == 1) ? bk : (mat == 2) ? bv : bs;
        BALL[J] = b[c * 256 + jj];
    }
}

// ---------------------------------------------------------------- degree (int)
__global__ __launch_bounds__(256) void degi_kernel(const int* __restrict__ ei,
                                                   int* __restrict__ degi) {
    int e = blockIdx.x * 256 + threadIdx.x;
    if (e < N_EDGES) atomicAdd(&degi[ei[N_EDGES + e]], 1);
}

// ---------------------------------------------------------------- prefix sum (1 block)
__global__ __launch_bounds__(256) void scan_kernel(const int* __restrict__ degi,
                                                   int* __restrict__ rowptr,
                                                   int* __restrict__ cursor) {
    __shared__ int part[256];
    int t = threadIdx.x;
    int base = t * 40;
    int s = 0;
    for (int i = 0; i < 40; ++i) { int idx = base + i; if (idx < N_NODES) s += degi[idx]; }
    part[t] = s;
    __syncthreads();
    for (int off = 1; off < 256; off <<= 1) {
        int v = part[t];
        int u = (t >= off) ? part[t - off] : 0;
        __syncthreads();
        part[t] = v + u;
        __syncthreads();
    }
    int run = (t == 0) ? 0 : part[t - 1];
    for (int i = 0; i < 40; ++i) {
        int idx = base + i;
        if (idx < N_NODES) { rowptr[idx] = run; cursor[idx] = run; run += degi[idx]; }
    }
    if (t == 255) rowptr[N_NODES] = N_EDGES;
}

// ---------------------------------------------------------------- CSR scatter
__global__ __launch_bounds__(256) void scatter_kernel(const int* __restrict__ ei,
                                                      int* __restrict__ cursor,
                                                      int* __restrict__ csr_eid,
                                                      int* __restrict__ csr_src) {
    int e = blockIdx.x * 256 + threadIdx.x;
    if (e < N_EDGES) {
        int d = ei[N_EDGES + e];
        int p = atomicAdd(&cursor[d], 1);
        csr_eid[p] = e;
        csr_src[p] = ei[e];
    }
}

// ---------------------------------------------------------------- fused MFMA GEMM with LDS staging
// C[10000][4096] = xb[10000][256] . WALL[4096][256]^T (+BALL), epilogue splits to QB/KB/VB/XCAT.
// 128x128 tile, BK=32, 4 waves (2x2), global_load_lds(16) staging, chunk-XOR LDS swizzle,
// XCD-aware block swizzle (2528 % 8 == 0 -> bijective).
__global__ __launch_bounds__(256) void gemm_tiled(
    const unsigned short* __restrict__ xb, const unsigned short* __restrict__ WALL,
    const float* __restrict__ BALL,
    unsigned short* __restrict__ QB, unsigned short* __restrict__ KB,
    unsigned short* __restrict__ VB, float* __restrict__ XCAT)
{
    __shared__ __align__(16) unsigned short As[BM * BK];   // 8 KB, [row][chunk^((row>>1)&3)]
    __shared__ __align__(16) unsigned short Bs[BN * BK];   // 8 KB

    const int bid = blockIdx.x;
    const int f = (bid & 7) * CPX + (bid >> 3);   // XCD swizzle: tn-fastest within XCD
    const int bm = (f >> 5) * BM, bn = (f & 31) * BN;

    const int tid = threadIdx.x, w = tid >> 6, lane = tid & 63;
    const int il = lane & 15, kg = lane >> 4;
    const int wr = w >> 1, wc = w & 1;

    const f4v zero = {0.f, 0.f, 0.f, 0.f};
    f4v acc[4][4];
    #pragma unroll
    for (int mi = 0; mi < 4; ++mi)
        #pragma unroll
        for (int ni = 0; ni < 4; ++ni) acc[mi][ni] = zero;

    // staging slot for this thread: sidx in [0,512), row = sidx>>2, chunk = sidx&3.
    // LDS slot (row,ch) holds global data chunk ch^((row>>1)&3)  (same XOR on read).
    for (int k0 = 0; k0 < DIM; k0 += BK) {
        #pragma unroll
        for (int t = 0; t < 2; ++t) {
            const int sidx = tid + t * 256;
            const int row = sidx >> 2, ch = sidx & 3;
            const int dc = ch ^ ((row >> 1) & 3);
            const int ldsbase = (t * 256 + w * 64) * 8;   // ushort idx; wave-uniform
            int ar = bm + row; ar = ar < N_NODES ? ar : N_NODES - 1;
            gload16(xb + (size_t)ar * DIM + k0 + dc * 8, As + ldsbase);
            gload16(WALL + (size_t)(bn + row) * DIM + k0 + dc * 8, Bs + ldsbase);
        }
        __syncthreads();   // compiler drains vmcnt before s_barrier

        s8v a[4], b[4];
        #pragma unroll
        for (int mi = 0; mi < 4; ++mi) {
            const int row = wr * 64 + mi * 16 + il;
            const int c2 = kg ^ ((row >> 1) & 3);
            a[mi] = *reinterpret_cast<const s8v*>(&As[row * 32 + c2 * 8]);
        }
        #pragma unroll
        for (int ni = 0; ni < 4; ++ni) {
            const int row = wc * 64 + ni * 16 + il;
            const int c2 = kg ^ ((row >> 1) & 3);
            b[ni] = *reinterpret_cast<const s8v*>(&Bs[row * 32 + c2 * 8]);
        }
        #pragma unroll
        for (int mi = 0; mi < 4; ++mi)
            #pragma unroll
            for (int ni = 0; ni < 4; ++ni)
                acc[mi][ni] = __builtin_amdgcn_mfma_f32_16x16x32_bf16(a[mi], b[ni], acc[mi][ni], 0, 0, 0);
        __syncthreads();
    }

    // Epilogue. D layout: col = lane&15, row(local) = (lane>>4)*4 + rr  [guide §3, m89/m91]
    #pragma unroll
    for (int ni = 0; ni < 4; ++ni) {
        const int col = bn + wc * 64 + ni * 16 + il;       // 0..4095
        const float bia = BALL[col];
        const int mat = col >> 10;
        const int cj = col & 1023;                          // c*256 + j
        unsigned short* O = (mat == 0) ? QB : (mat == 1) ? KB : VB;
        #pragma unroll
        for (int mi = 0; mi < 4; ++mi) {
            const int rbase = bm + wr * 64 + mi * 16 + kg * 4;
            #pragma unroll
            for (int rr = 0; rr < 4; ++rr) {
                const int r = rbase + rr;
                if (r < N_NODES) {
                    const float v = acc[mi][ni][rr] + bia;
                    if (mat == 3) XCAT[(size_t)r * 1024 + cj] = v;
                    else          O[((size_t)(cj >> 8) * N_NODES + r) * DIM + (cj & 255)] = f2bf(v);
                }
            }
        }
    }
}

// ---------------------------------------------------------------- fused CSR edge pass
// block = one dst node, wave = one channel. bf16 Q/K/V gathers (8B/lane).
// dot1 = q.k + av*(q.we) [q.we hoisted]; agg = we (.) sum(av*v) [we hoisted].
__global__ __launch_bounds__(256) void edge_fused(
    const int* __restrict__ rowptr, const int* __restrict__ csr_eid,
    const int* __restrict__ csr_src,
    const float* __restrict__ adj, const float* __restrict__ We,
    const unsigned short* __restrict__ QB, const unsigned short* __restrict__ KB,
    const unsigned short* __restrict__ VB,
    float* __restrict__ XCAT, float* __restrict__ ALPHA)
{
    const int n = blockIdx.x;
    const int c = threadIdx.x >> 6, lane = threadIdx.x & 63, col = lane * 4;

    const size_t nb = ((size_t)c * N_NODES + n) * DIM + col;
    float4 qd = ldbf4(QB + nb);
    float4 kd = ldbf4(KB + nb);
    float4 we = ldf4(&We[c * DIM + col]);

    float qdwe = qd.x * we.x + qd.y * we.y + qd.z * we.z + qd.w * we.w;
    #pragma unroll
    for (int off = 1; off <= 8; off <<= 1) qdwe += __shfl_xor(qdwe, off, 64);

    const float* adjc = adj + (size_t)c * N_EDGES;
    float4 acc = make_float4(0.f, 0.f, 0.f, 0.f);
    const int p0 = rowptr[n], p1 = rowptr[n + 1];
    for (int p = p0; p < p1; ++p) {
        int eid = csr_eid[p];
        int s   = csr_src[p];
        float av = adjc[eid];
        size_t sb = ((size_t)c * N_NODES + s) * DIM + col;
        float4 ks = ldbf4(KB + sb);
        float4 qs = ldbf4(QB + sb);
        float4 vs = ldbf4(VB + sb);
        float d1 = qd.x*ks.x + qd.y*ks.y + qd.z*ks.z + qd.w*ks.w;
        float d2 = qs.x*kd.x + qs.y*kd.y + qs.z*kd.z + qs.w*kd.w;
        #pragma unroll
        for (int off = 1; off <= 8; off <<= 1) {
            d1 += __shfl_xor(d1, off, 64);
            d2 += __shfl_xor(d2, off, 64);
        }
        d1 += av * qdwe;
        float al = 0.5f * (tanhf(d1 * 0.125f) + tanhf(d2 * 0.125f));
        al += __shfl_xor(al, 16, 64);
        al += __shfl_xor(al, 32, 64);
        if (lane == 0) ALPHA[(size_t)eid * NCH + c] = al * 0.25f;
        acc.x += av * vs.x; acc.y += av * vs.y;
        acc.z += av * vs.z; acc.w += av * vs.w;
    }
    float inv = 1.0f / fmaxf((float)(p1 - p0), 1.0f);
    float* xc = &XCAT[(size_t)n * (NCH * DIM) + c * DIM + col];
    float4 xv = ldf4(xc);
    xv.x += acc.x * we.x * inv; xv.y += acc.y * we.y * inv;
    xv.z += acc.z * we.z * inv; xv.w += acc.w * we.w * inv;
    *reinterpret_cast<float4*>(xc) = xv;
}

// ---------------------------------------------------------------- node MLP (1024->8 elu ->256 tanh)
__global__ __launch_bounds__(256) void node_final(
    const float* __restrict__ XCAT,
    const float* __restrict__ W1, const float* __restrict__ b1,
    const float* __restrict__ W2, const float* __restrict__ b2,
    float* __restrict__ out)
{
    int n    = (blockIdx.x * 256 + threadIdx.x) >> 6;
    int lane = threadIdx.x & 63;
    const float* xr = XCAT + (size_t)n * (NCH * DIM);
    float4 xv[4];
    #pragma unroll
    for (int t = 0; t < 4; ++t) xv[t] = ldf4(&xr[t * 256 + lane * 4]);
    float h[HIDD];
    #pragma unroll
    for (int j = 0; j < HIDD; ++j) {
        const float* wr = W1 + j * (NCH * DIM);
        float p = 0.f;
        #pragma unroll
        for (int t = 0; t < 4; ++t) {
            float4 wv = ldf4(&wr[t * 256 + lane * 4]);
            p += xv[t].x*wv.x + xv[t].y*wv.y + xv[t].z*wv.z + xv[t].w*wv.w;
        }
        #pragma unroll
        for (int off = 1; off < 64; off <<= 1) p += __shfl_xor(p, off, 64);
        float z = p + b1[j];
        h[j] = z > 0.f ? z : (expf(z) - 1.f);
    }
    float rr[4];
    #pragma unroll
    for (int i = 0; i < 4; ++i) {
        int colj = lane * 4 + i;
        float z = b2[colj];
        #pragma unroll
        for (int j = 0; j < HIDD; ++j) z += h[j] * W2[colj * HIDD + j];
        rr[i] = tanhf(z);
    }
    float4 r; r.x = rr[0]; r.y = rr[1]; r.z = rr[2]; r.w = rr[3];
    *reinterpret_cast<float4*>(&out[n * DIM + lane * 4]) = r;
}

// ---------------------------------------------------------------- edge MLP (8->8->8->4)
__global__ __launch_bounds__(256) void edge_mlp(
    const float* __restrict__ ALPHA, const float* __restrict__ adj,
    const float* __restrict__ W1, const float* __restrict__ b1,
    const float* __restrict__ W2, const float* __restrict__ b2,
    const float* __restrict__ W3, const float* __restrict__ b3,
    float* __restrict__ out)
{
    int e = blockIdx.x * 256 + threadIdx.x;
    if (e >= N_EDGES) return;
    float in[8];
    #pragma unroll
    for (int c = 0; c < NCH; ++c) in[c] = ALPHA[(size_t)e * NCH + c];
    #pragma unroll
    for (int c = 0; c < NCH; ++c) in[4 + c] = adj[(size_t)c * N_EDGES + e];
    float h1[8], h2[8];
    #pragma unroll
    for (int j = 0; j < 8; ++j) {
        float z = b1[j];
        #pragma unroll
        for (int i = 0; i < 8; ++i) z += W1[j*8 + i] * in[i];
        h1[j] = z > 0.f ? z : (expf(z) - 1.f);
    }
    #pragma unroll
    for (int j = 0; j < 8; ++j) {
        float z = b2[j];
        #pragma unroll
        for (int i = 0; i < 8; ++i) z += W2[j*8 + i] * h1[i];
        h2[j] = z > 0.f ? z : (expf(z) - 1.f);
    }
    #pragma unroll
    for (int o = 0; o < 4; ++o) {
        float z = b3[o];
        #pragma unroll
        for (int j = 0; j < 8; ++j) z += W3[o*8 + j] * h2[j];
        out[(size_t)o * N_EDGES + e] = z;
    }
}

// ---------------------------------------------------------------- launch
extern "C" void kernel_launch(void* const* d_in, const int* in_sizes, int n_in,
                              void* d_out, int out_size, void* d_ws, size_t ws_size,
                              hipStream_t stream) {
    const float* x    = (const float*)d_in[0];
    const int*   ei   = (const int*)  d_in[1];
    const float* adj  = (const float*)d_in[2];
    const float* Wq   = (const float*)d_in[4];
    const float* bq   = (const float*)d_in[5];
    const float* Wk   = (const float*)d_in[6];
    const float* bk   = (const float*)d_in[7];
    const float* Wv   = (const float*)d_in[8];
    const float* bv   = (const float*)d_in[9];
    const float* We   = (const float*)d_in[10];
    const float* Wsk  = (const float*)d_in[11];
    const float* bsk  = (const float*)d_in[12];
    const float* Wmc1 = (const float*)d_in[13];
    const float* bmc1 = (const float*)d_in[14];
    const float* Wmc2 = (const float*)d_in[15];
    const float* bmc2 = (const float*)d_in[16];
    const float* Wm1  = (const float*)d_in[17];
    const float* bm1  = (const float*)d_in[18];
    const float* Wm2  = (const float*)d_in[19];
    const float* bm2  = (const float*)d_in[20];
    const float* Wm3  = (const float*)d_in[21];
    const float* bm3  = (const float*)d_in[22];

    // ---- workspace layout (~113 MB total)
    char* w = (char*)d_ws;
    unsigned short* xb   = (unsigned short*)w; w += (size_t)N_NODES * DIM * 2;        // 5.12 MB
    unsigned short* WALL = (unsigned short*)w; w += (size_t)4096 * DIM * 2;           // 2.10 MB
    float*          BALL = (float*)w;          w += (size_t)4096 * 4;                 // 16 KB
    unsigned short* QB   = (unsigned short*)w; w += (size_t)NCH * N_NODES * DIM * 2;  // 20.48 MB
    unsigned short* KB   = (unsigned short*)w; w += (size_t)NCH * N_NODES * DIM * 2;
    unsigned short* VB   = (unsigned short*)w; w += (size_t)NCH * N_NODES * DIM * 2;
    float* XCAT  = (float*)w; w += (size_t)N_NODES * NCH * DIM * 4;                   // 40.96 MB
    float* ALPHA = (float*)w; w += (size_t)N_EDGES * NCH * 4;                         // 1.60 MB
    int* degi    = (int*)w; w += N_NODES * 4;
    int* rowptr  = (int*)w; w += (N_NODES + 1) * 4;
    int* cursor  = (int*)w; w += N_NODES * 4;
    int* csr_eid = (int*)w; w += N_EDGES * 4;
    int* csr_src = (int*)w; w += N_EDGES * 4;

    float* xout   = (float*)d_out;
    float* mlpout = xout + (size_t)N_NODES * DIM;

    // ---- bf16 conversions / weight packing
    cvt_bf16<<<(N_NODES * DIM / 8 + 255) / 256, 256, 0, stream>>>(x, xb, N_NODES * DIM / 8);
    pack_w<<<512, 256, 0, stream>>>(Wq, Wk, Wv, Wsk, bq, bk, bv, bsk, WALL, BALL);

    // ---- CSR build
    hipMemsetAsync(degi, 0, N_NODES * sizeof(int), stream);
    degi_kernel<<<(N_EDGES + 255) / 256, 256, 0, stream>>>(ei, degi);
    scan_kernel<<<1, 256, 0, stream>>>(degi, rowptr, cursor);
    scatter_kernel<<<(N_EDGES + 255) / 256, 256, 0, stream>>>(ei, cursor, csr_eid, csr_src);

    // ---- all 16 GEMMs as one fused LDS-tiled MFMA GEMM
    gemm_tiled<<<NWG, 256, 0, stream>>>(xb, WALL, BALL, QB, KB, VB, XCAT);

    // ---- fused edge pass: all channels, one launch
    edge_fused<<<N_NODES, 256, 0, stream>>>(rowptr, csr_eid, csr_src, adj, We,
                                            QB, KB, VB, XCAT, ALPHA);

    node_final<<<N_NODES / 4, 256, 0, stream>>>(XCAT, Wmc1, bmc1, Wmc2, bmc2, xout);
    edge_mlp<<<(N_EDGES + 255) / 256, 256, 0, stream>>>(ALPHA, adj, Wm1, bm1,
                                                        Wm2, bm2, Wm3, bm3, mlpout);
}

// Round 11
// 262.585 us; speedup vs baseline: 6.7335x; 1.0126x over previous
//
#include <hip/hip_runtime.h>
#include <math.h>

#define N_NODES 10000
#define N_EDGES 100000
#define DIM 256
#define NCH 4
#define HIDD 8
#define OUTD 4

#define BM 128
#define BN 128
#define BK 32
#define NTM 79              // ceil(10000/128)
#define NTN 32              // 4096/128
#define NWG (NTM * NTN)     // 2528, divisible by 8
#define CPX (NWG / 8)       // 316

typedef short s8v __attribute__((ext_vector_type(8)));   // 8 bf16 in 4 VGPRs
typedef float f4v __attribute__((ext_vector_type(4)));   // MFMA accumulator

__device__ __forceinline__ float4 ldf4(const float* p) {
    return *reinterpret_cast<const float4*>(p);
}
__device__ __forceinline__ unsigned short f2bf(float f) {  // RNE f32->bf16
    unsigned int u = __float_as_uint(f);
    u += 0x7FFFu + ((u >> 16) & 1u);
    return (unsigned short)(u >> 16);
}
__device__ __forceinline__ float bf2f(unsigned short b) {
    return __uint_as_float(((unsigned int)b) << 16);
}
__device__ __forceinline__ float4 ldbf4(const unsigned short* p) {
    ushort4 u = *reinterpret_cast<const ushort4*>(p);
    float4 f;
    f.x = bf2f(u.x); f.y = bf2f(u.y); f.z = bf2f(u.z); f.w = bf2f(u.w);
    return f;
}
// fast tanh: (e-1)/(e+1), e=exp(2x); ~6 VALU ops vs ~50 for libm tanhf.
// clamp keeps exp finite; |err| ~1e-5, far under the bf16 noise floor.
__device__ __forceinline__ float fast_tanh(float x) {
    float xc = fminf(fmaxf(x, -15.f), 15.f);
    float e = __expf(2.f * xc);
    return (e - 1.f) * __builtin_amdgcn_rcpf(e + 1.f);
}
__device__ __forceinline__ float fast_elu(float z) {
    return z > 0.f ? z : (__expf(z) - 1.f);
}
// async global->LDS, 16B per lane; lds base must be wave-uniform (HW adds lane*16)
__device__ __forceinline__ void gload16(const unsigned short* g, unsigned short* l) {
    __builtin_amdgcn_global_load_lds(
        (const __attribute__((address_space(1))) unsigned int*)(const void*)g,
        (__attribute__((address_space(3))) unsigned int*)(void*)l, 16, 0, 0);
}

// ---------------------------------------------------------------- f32 -> bf16
__global__ __launch_bounds__(256) void cvt_bf16(const float* __restrict__ src,
                                                unsigned short* __restrict__ dst, int n8) {
    int i = blockIdx.x * 256 + threadIdx.x;
    if (i >= n8) return;
    float4 v0 = ldf4(src + (size_t)i * 8);
    float4 v1 = ldf4(src + (size_t)i * 8 + 4);
    ushort4 o0, o1;
    o0.x = f2bf(v0.x); o0.y = f2bf(v0.y); o0.z = f2bf(v0.z); o0.w = f2bf(v0.w);
    o1.x = f2bf(v1.x); o1.y = f2bf(v1.y); o1.z = f2bf(v1.z); o1.w = f2bf(v1.w);
    *reinterpret_cast<ushort4*>(dst + (size_t)i * 8) = o0;
    *reinterpret_cast<ushort4*>(dst + (size_t)i * 8 + 4) = o1;
}

// ---------------------------------------------------------------- pack all 16 W mats -> WALL[4096][256] bf16 (+BALL)
// J = mat*1024 + c*256 + j ; WALL[J][k] = W_mat[c][j][k]
__global__ __launch_bounds__(256) void pack_w(
    const float* __restrict__ Wq, const float* __restrict__ Wk,
    const float* __restrict__ Wv, const float* __restrict__ Ws,
    const float* __restrict__ bq, const float* __restrict__ bk,
    const float* __restrict__ bv, const float* __restrict__ bs,
    unsigned short* __restrict__ WALL, float* __restrict__ BALL)
{
    int i = blockIdx.x * 256 + threadIdx.x;       // over 4096*256/8 = 131072
    int J = i >> 5;
    int kk = (i & 31) * 8;
    int mat = J >> 10, c = (J >> 8) & 3, jj = J & 255;
    const float* W = (mat == 0) ? Wq : (mat == 1) ? Wk : (mat == 2) ? Wv : Ws;
    const float* src = W + (size_t)c * 65536 + jj * 256 + kk;
    float4 v0 = ldf4(src);
    float4 v1 = ldf4(src + 4);
    ushort4 o0, o1;
    o0.x = f2bf(v0.x); o0.y = f2bf(v0.y); o0.z = f2bf(v0.z); o0.w = f2bf(v0.w);
    o1.x = f2bf(v1.x); o1.y = f2bf(v1.y); o1.z = f2bf(v1.z); o1.w = f2bf(v1.w);
    *reinterpret_cast<ushort4*>(WALL + (size_t)J * 256 + kk) = o0;
    *reinterpret_cast<ushort4*>(WALL + (size_t)J * 256 + kk + 4) = o1;
    if (kk == 0) {
        const float* b = (mat == 0) ? bq : (mat == 1) ? bk : (mat == 2) ? bv : bs;
        BALL[J] = b[c * 256 + jj];
    }
}

// ---------------------------------------------------------------- degree (int)
__global__ __launch_bounds__(256) void degi_kernel(const int* __restrict__ ei,
                                                   int* __restrict__ degi) {
    int e = blockIdx.x * 256 + threadIdx.x;
    if (e < N_EDGES) atomicAdd(&degi[ei[N_EDGES + e]], 1);
}

// ---------------------------------------------------------------- prefix sum (1 block)
__global__ __launch_bounds__(256) void scan_kernel(const int* __restrict__ degi,
                                                   int* __restrict__ rowptr,
                                                   int* __restrict__ cursor) {
    __shared__ int part[256];
    int t = threadIdx.x;
    int base = t * 40;
    int s = 0;
    for (int i = 0; i < 40; ++i) { int idx = base + i; if (idx < N_NODES) s += degi[idx]; }
    part[t] = s;
    __syncthreads();
    for (int off = 1; off < 256; off <<= 1) {
        int v = part[t];
        int u = (t >= off) ? part[t - off] : 0;
        __syncthreads();
        part[t] = v + u;
        __syncthreads();
    }
    int run = (t == 0) ? 0 : part[t - 1];
    for (int i = 0; i < 40; ++i) {
        int idx = base + i;
        if (idx < N_NODES) { rowptr[idx] = run; cursor[idx] = run; run += degi[idx]; }
    }
    if (t == 255) rowptr[N_NODES] = N_EDGES;
}

// ---------------------------------------------------------------- CSR scatter
__global__ __launch_bounds__(256) void scatter_kernel(const int* __restrict__ ei,
                                                      int* __restrict__ cursor,
                                                      int* __restrict__ csr_eid,
                                                      int* __restrict__ csr_src) {
    int e = blockIdx.x * 256 + threadIdx.x;
    if (e < N_EDGES) {
        int d = ei[N_EDGES + e];
        int p = atomicAdd(&cursor[d], 1);
        csr_eid[p] = e;
        csr_src[p] = ei[e];
    }
}

// ---------------------------------------------------------------- fused MFMA GEMM with LDS staging
// C[10000][4096] = xb[10000][256] . WALL[4096][256]^T (+BALL); epilogue splits to
// QKV[c][node][{q,k,v}][256] (bf16, interleaved for edge-gather locality) and XCAT (f32).
__global__ __launch_bounds__(256) void gemm_tiled(
    const unsigned short* __restrict__ xb, const unsigned short* __restrict__ WALL,
    const float* __restrict__ BALL,
    unsigned short* __restrict__ QKV, float* __restrict__ XCAT)
{
    __shared__ __align__(16) unsigned short As[BM * BK];   // 8 KB, [row][chunk^((row>>1)&3)]
    __shared__ __align__(16) unsigned short Bs[BN * BK];   // 8 KB

    const int bid = blockIdx.x;
    const int f = (bid & 7) * CPX + (bid >> 3);   // XCD swizzle: bijective (2528 % 8 == 0)
    const int bm = (f >> 5) * BM, bn = (f & 31) * BN;

    const int tid = threadIdx.x, w = tid >> 6, lane = tid & 63;
    const int il = lane & 15, kg = lane >> 4;
    const int wr = w >> 1, wc = w & 1;

    const f4v zero = {0.f, 0.f, 0.f, 0.f};
    f4v acc[4][4];
    #pragma unroll
    for (int mi = 0; mi < 4; ++mi)
        #pragma unroll
        for (int ni = 0; ni < 4; ++ni) acc[mi][ni] = zero;

    // staging slot: sidx in [0,512), row = sidx>>2, chunk = sidx&3.
    // LDS slot (row,ch) holds global chunk ch^((row>>1)&3)  (same XOR on read).
    for (int k0 = 0; k0 < DIM; k0 += BK) {
        #pragma unroll
        for (int t = 0; t < 2; ++t) {
            const int sidx = tid + t * 256;
            const int row = sidx >> 2, ch = sidx & 3;
            const int dc = ch ^ ((row >> 1) & 3);
            const int ldsbase = (t * 256 + w * 64) * 8;   // ushort idx; wave-uniform
            int ar = bm + row; ar = ar < N_NODES ? ar : N_NODES - 1;
            gload16(xb + (size_t)ar * DIM + k0 + dc * 8, As + ldsbase);
            gload16(WALL + (size_t)(bn + row) * DIM + k0 + dc * 8, Bs + ldsbase);
        }
        __syncthreads();   // compiler drains vmcnt before s_barrier

        s8v a[4], b[4];
        #pragma unroll
        for (int mi = 0; mi < 4; ++mi) {
            const int row = wr * 64 + mi * 16 + il;
            const int c2 = kg ^ ((row >> 1) & 3);
            a[mi] = *reinterpret_cast<const s8v*>(&As[row * 32 + c2 * 8]);
        }
        #pragma unroll
        for (int ni = 0; ni < 4; ++ni) {
            const int row = wc * 64 + ni * 16 + il;
            const int c2 = kg ^ ((row >> 1) & 3);
            b[ni] = *reinterpret_cast<const s8v*>(&Bs[row * 32 + c2 * 8]);
        }
        #pragma unroll
        for (int mi = 0; mi < 4; ++mi)
            #pragma unroll
            for (int ni = 0; ni < 4; ++ni)
                acc[mi][ni] = __builtin_amdgcn_mfma_f32_16x16x32_bf16(a[mi], b[ni], acc[mi][ni], 0, 0, 0);
        __syncthreads();
    }

    // Epilogue. D layout: col = lane&15, row(local) = (lane>>4)*4 + rr  [guide §3, m89/m91]
    #pragma unroll
    for (int ni = 0; ni < 4; ++ni) {
        const int col = bn + wc * 64 + ni * 16 + il;       // 0..4095
        const float bia = BALL[col];
        const int mat = col >> 10;
        const int cj = col & 1023;                          // c*256 + j
        const int cc = cj >> 8, jj = cj & 255;
        #pragma unroll
        for (int mi = 0; mi < 4; ++mi) {
            const int rbase = bm + wr * 64 + mi * 16 + kg * 4;
            #pragma unroll
            for (int rr = 0; rr < 4; ++rr) {
                const int r = rbase + rr;
                if (r < N_NODES) {
                    const float v = acc[mi][ni][rr] + bia;
                    if (mat == 3) XCAT[(size_t)r * 1024 + cj] = v;
                    else QKV[(((size_t)cc * N_NODES + r) * 3 + mat) * DIM + jj] = f2bf(v);
                }
            }
        }
    }
}

// ---------------------------------------------------------------- fused CSR edge pass
// block = one dst node, wave = one channel. QKV interleaved: per (c,node) 1536B
// contiguous {q,k,v} -> one region per src gather. fast_tanh replaces libm tanhf.
__global__ __launch_bounds__(256) void edge_fused(
    const int* __restrict__ rowptr, const int* __restrict__ csr_eid,
    const int* __restrict__ csr_src,
    const float* __restrict__ adj, const float* __restrict__ We,
    const unsigned short* __restrict__ QKV,
    float* __restrict__ XCAT, float* __restrict__ ALPHA)
{
    const int n = blockIdx.x;
    const int c = threadIdx.x >> 6, lane = threadIdx.x & 63, col = lane * 4;

    const size_t nbase = ((size_t)c * N_NODES + n) * 3 * DIM;
    float4 qd = ldbf4(QKV + nbase + col);
    float4 kd = ldbf4(QKV + nbase + DIM + col);
    float4 we = ldf4(&We[c * DIM + col]);

    float qdwe = qd.x * we.x + qd.y * we.y + qd.z * we.z + qd.w * we.w;
    #pragma unroll
    for (int off = 1; off <= 8; off <<= 1) qdwe += __shfl_xor(qdwe, off, 64);

    const float* adjc = adj + (size_t)c * N_EDGES;
    float4 acc = make_float4(0.f, 0.f, 0.f, 0.f);
    const int p0 = rowptr[n], p1 = rowptr[n + 1];
    for (int p = p0; p < p1; ++p) {
        int eid = csr_eid[p];
        int s   = csr_src[p];
        float av = adjc[eid];
        const size_t sbase = ((size_t)c * N_NODES + s) * 3 * DIM;
        float4 qs = ldbf4(QKV + sbase + col);
        float4 ks = ldbf4(QKV + sbase + DIM + col);
        float4 vs = ldbf4(QKV + sbase + 2 * DIM + col);
        float d1 = qd.x*ks.x + qd.y*ks.y + qd.z*ks.z + qd.w*ks.w;
        float d2 = qs.x*kd.x + qs.y*kd.y + qs.z*kd.z + qs.w*kd.w;
        #pragma unroll
        for (int off = 1; off <= 8; off <<= 1) {
            d1 += __shfl_xor(d1, off, 64);
            d2 += __shfl_xor(d2, off, 64);
        }
        d1 += av * qdwe;
        float al = 0.5f * (fast_tanh(d1 * 0.125f) + fast_tanh(d2 * 0.125f));
        al += __shfl_xor(al, 16, 64);
        al += __shfl_xor(al, 32, 64);
        if (lane == 0) ALPHA[(size_t)eid * NCH + c] = al * 0.25f;
        acc.x += av * vs.x; acc.y += av * vs.y;
        acc.z += av * vs.z; acc.w += av * vs.w;
    }
    float inv = 1.0f / fmaxf((float)(p1 - p0), 1.0f);
    float* xc = &XCAT[(size_t)n * (NCH * DIM) + c * DIM + col];
    float4 xv = ldf4(xc);
    xv.x += acc.x * we.x * inv; xv.y += acc.y * we.y * inv;
    xv.z += acc.z * we.z * inv; xv.w += acc.w * we.w * inv;
    *reinterpret_cast<float4*>(xc) = xv;
}

// ---------------------------------------------------------------- node MLP (1024->8 elu ->256 tanh)
__global__ __launch_bounds__(256) void node_final(
    const float* __restrict__ XCAT,
    const float* __restrict__ W1, const float* __restrict__ b1,
    const float* __restrict__ W2, const float* __restrict__ b2,
    float* __restrict__ out)
{
    int n    = (blockIdx.x * 256 + threadIdx.x) >> 6;
    int lane = threadIdx.x & 63;
    const float* xr = XCAT + (size_t)n * (NCH * DIM);
    float4 xv[4];
    #pragma unroll
    for (int t = 0; t < 4; ++t) xv[t] = ldf4(&xr[t * 256 + lane * 4]);
    float h[HIDD];
    #pragma unroll
    for (int j = 0; j < HIDD; ++j) {
        const float* wr = W1 + j * (NCH * DIM);
        float p = 0.f;
        #pragma unroll
        for (int t = 0; t < 4; ++t) {
            float4 wv = ldf4(&wr[t * 256 + lane * 4]);
            p += xv[t].x*wv.x + xv[t].y*wv.y + xv[t].z*wv.z + xv[t].w*wv.w;
        }
        #pragma unroll
        for (int off = 1; off < 64; off <<= 1) p += __shfl_xor(p, off, 64);
        h[j] = fast_elu(p + b1[j]);
    }
    float rr[4];
    #pragma unroll
    for (int i = 0; i < 4; ++i) {
        int colj = lane * 4 + i;
        float z = b2[colj];
        #pragma unroll
        for (int j = 0; j < HIDD; ++j) z += h[j] * W2[colj * HIDD + j];
        rr[i] = fast_tanh(z);
    }
    float4 r; r.x = rr[0]; r.y = rr[1]; r.z = rr[2]; r.w = rr[3];
    *reinterpret_cast<float4*>(&out[n * DIM + lane * 4]) = r;
}

// ---------------------------------------------------------------- edge MLP (8->8->8->4)
__global__ __launch_bounds__(256) void edge_mlp(
    const float* __restrict__ ALPHA, const float* __restrict__ adj,
    const float* __restrict__ W1, const float* __restrict__ b1,
    const float* __restrict__ W2, const float* __restrict__ b2,
    const float* __restrict__ W3, const float* __restrict__ b3,
    float* __restrict__ out)
{
    int e = blockIdx.x * 256 + threadIdx.x;
    if (e >= N_EDGES) return;
    float in[8];
    #pragma unroll
    for (int c = 0; c < NCH; ++c) in[c] = ALPHA[(size_t)e * NCH + c];
    #pragma unroll
    for (int c = 0; c < NCH; ++c) in[4 + c] = adj[(size_t)c * N_EDGES + e];
    float h1[8], h2[8];
    #pragma unroll
    for (int j = 0; j < 8; ++j) {
        float z = b1[j];
        #pragma unroll
        for (int i = 0; i < 8; ++i) z += W1[j*8 + i] * in[i];
        h1[j] = fast_elu(z);
    }
    #pragma unroll
    for (int j = 0; j < 8; ++j) {
        float z = b2[j];
        #pragma unroll
        for (int i = 0; i < 8; ++i) z += W2[j*8 + i] * h1[i];
        h2[j] = fast_elu(z);
    }
    #pragma unroll
    for (int o = 0; o < 4; ++o) {
        float z = b3[o];
        #pragma unroll
        for (int j = 0; j < 8; ++j) z += W3[o*8 + j] * h2[j];
        out[(size_t)o * N_EDGES + e] = z;
    }
}

// ---------------------------------------------------------------- launch
extern "C" void kernel_launch(void* const* d_in, const int* in_sizes, int n_in,
                              void* d_out, int out_size, void* d_ws, size_t ws_size,
                              hipStream_t stream) {
    const float* x    = (const float*)d_in[0];
    const int*   ei   = (const int*)  d_in[1];
    const float* adj  = (const float*)d_in[2];
    const float* Wq   = (const float*)d_in[4];
    const float* bq   = (const float*)d_in[5];
    const float* Wk   = (const float*)d_in[6];
    const float* bk   = (const float*)d_in[7];
    const float* Wv   = (const float*)d_in[8];
    const float* bv   = (const float*)d_in[9];
    const float* We   = (const float*)d_in[10];
    const float* Wsk  = (const float*)d_in[11];
    const float* bsk  = (const float*)d_in[12];
    const float* Wmc1 = (const float*)d_in[13];
    const float* bmc1 = (const float*)d_in[14];
    const float* Wmc2 = (const float*)d_in[15];
    const float* bmc2 = (const float*)d_in[16];
    const float* Wm1  = (const float*)d_in[17];
    const float* bm1  = (const float*)d_in[18];
    const float* Wm2  = (const float*)d_in[19];
    const float* bm2  = (const float*)d_in[20];
    const float* Wm3  = (const float*)d_in[21];
    const float* bm3  = (const float*)d_in[22];

    // ---- workspace layout (~113 MB total)
    char* w = (char*)d_ws;
    unsigned short* xb   = (unsigned short*)w; w += (size_t)N_NODES * DIM * 2;        // 5.12 MB
    unsigned short* WALL = (unsigned short*)w; w += (size_t)4096 * DIM * 2;           // 2.10 MB
    float*          BALL = (float*)w;          w += (size_t)4096 * 4;                 // 16 KB
    unsigned short* QKV  = (unsigned short*)w; w += (size_t)NCH * N_NODES * 3 * DIM * 2; // 61.44 MB
    float* XCAT  = (float*)w; w += (size_t)N_NODES * NCH * DIM * 4;                   // 40.96 MB
    float* ALPHA = (float*)w; w += (size_t)N_EDGES * NCH * 4;                         // 1.60 MB
    int* degi    = (int*)w; w += N_NODES * 4;
    int* rowptr  = (int*)w; w += (N_NODES + 1) * 4;
    int* cursor  = (int*)w; w += N_NODES * 4;
    int* csr_eid = (int*)w; w += N_EDGES * 4;
    int* csr_src = (int*)w; w += N_EDGES * 4;

    float* xout   = (float*)d_out;
    float* mlpout = xout + (size_t)N_NODES * DIM;

    // ---- bf16 conversions / weight packing
    cvt_bf16<<<(N_NODES * DIM / 8 + 255) / 256, 256, 0, stream>>>(x, xb, N_NODES * DIM / 8);
    pack_w<<<512, 256, 0, stream>>>(Wq, Wk, Wv, Wsk, bq, bk, bv, bsk, WALL, BALL);

    // ---- CSR build
    hipMemsetAsync(degi, 0, N_NODES * sizeof(int), stream);
    degi_kernel<<<(N_EDGES + 255) / 256, 256, 0, stream>>>(ei, degi);
    scan_kernel<<<1, 256, 0, stream>>>(degi, rowptr, cursor);
    scatter_kernel<<<(N_EDGES + 255) / 256, 256, 0, stream>>>(ei, cursor, csr_eid, csr_src);

    // ---- all 16 GEMMs as one fused LDS-tiled MFMA GEMM
    gemm_tiled<<<NWG, 256, 0, stream>>>(xb, WALL, BALL, QKV, XCAT);

    // ---- fused edge pass: all channels, one launch
    edge_fused<<<N_NODES, 256, 0, stream>>>(rowptr, csr_eid, csr_src, adj, We,
                                            QKV, XCAT, ALPHA);

    node_final<<<N_NODES / 4, 256, 0, stream>>>(XCAT, Wmc1, bmc1, Wmc2, bmc2, xout);
    edge_mlp<<<(N_EDGES + 255) / 256, 256, 0, stream>>>(ALPHA, adj, Wm1, bm1,
                                                        Wm2, bm2, Wm3, bm3, mlpout);
}

// Round 12
// 258.390 us; speedup vs baseline: 6.8428x; 1.0162x over previous
//
#include <hip/hip_runtime.h>
#include <math.h>

#define N_NODES 10000
#define N_EDGES 100000
#define DIM 256
#define NCH 4
#define HIDD 8
#define OUTD 4

#define BM 128
#define BN 128
#define BK 32
#define NTM 79              // ceil(10000/128)
#define NTN 32              // 4096/128
#define NWG (NTM * NTN)     // 2528, divisible by 8
#define CPX (NWG / 8)       // 316

typedef short s8v __attribute__((ext_vector_type(8)));   // 8 bf16 in 4 VGPRs
typedef float f4v __attribute__((ext_vector_type(4)));   // MFMA accumulator

__device__ __forceinline__ float4 ldf4(const float* p) {
    return *reinterpret_cast<const float4*>(p);
}
__device__ __forceinline__ unsigned short f2bf(float f) {  // RNE f32->bf16
    unsigned int u = __float_as_uint(f);
    u += 0x7FFFu + ((u >> 16) & 1u);
    return (unsigned short)(u >> 16);
}
__device__ __forceinline__ float bf2f(unsigned short b) {
    return __uint_as_float(((unsigned int)b) << 16);
}
__device__ __forceinline__ float4 ldbf4(const unsigned short* p) {
    ushort4 u = *reinterpret_cast<const ushort4*>(p);
    float4 f;
    f.x = bf2f(u.x); f.y = bf2f(u.y); f.z = bf2f(u.z); f.w = bf2f(u.w);
    return f;
}
// fast tanh: (e-1)/(e+1), e=exp(2x); ~6 VALU ops vs ~50 for libm tanhf.
__device__ __forceinline__ float fast_tanh(float x) {
    float xc = fminf(fmaxf(x, -15.f), 15.f);
    float e = __expf(2.f * xc);
    return (e - 1.f) * __builtin_amdgcn_rcpf(e + 1.f);
}
__device__ __forceinline__ float fast_elu(float z) {
    return z > 0.f ? z : (__expf(z) - 1.f);
}
// async global->LDS, 16B per lane; lds base must be wave-uniform (HW adds lane*16)
__device__ __forceinline__ void gload16(const unsigned short* g, unsigned short* l) {
    __builtin_amdgcn_global_load_lds(
        (const __attribute__((address_space(1))) unsigned int*)(const void*)g,
        (__attribute__((address_space(3))) unsigned int*)(void*)l, 16, 0, 0);
}

// ---------------------------------------------------------------- f32 -> bf16
__global__ __launch_bounds__(256) void cvt_bf16(const float* __restrict__ src,
                                                unsigned short* __restrict__ dst, int n8) {
    int i = blockIdx.x * 256 + threadIdx.x;
    if (i >= n8) return;
    float4 v0 = ldf4(src + (size_t)i * 8);
    float4 v1 = ldf4(src + (size_t)i * 8 + 4);
    ushort4 o0, o1;
    o0.x = f2bf(v0.x); o0.y = f2bf(v0.y); o0.z = f2bf(v0.z); o0.w = f2bf(v0.w);
    o1.x = f2bf(v1.x); o1.y = f2bf(v1.y); o1.z = f2bf(v1.z); o1.w = f2bf(v1.w);
    *reinterpret_cast<ushort4*>(dst + (size_t)i * 8) = o0;
    *reinterpret_cast<ushort4*>(dst + (size_t)i * 8 + 4) = o1;
}

// ---------------------------------------------------------------- pack all 16 W mats -> WALL[4096][256] bf16 (+BALL)
// J = mat*1024 + c*256 + j ; WALL[J][k] = W_mat[c][j][k]
__global__ __launch_bounds__(256) void pack_w(
    const float* __restrict__ Wq, const float* __restrict__ Wk,
    const float* __restrict__ Wv, const float* __restrict__ Ws,
    const float* __restrict__ bq, const float* __restrict__ bk,
    const float* __restrict__ bv, const float* __restrict__ bs,
    unsigned short* __restrict__ WALL, float* __restrict__ BALL)
{
    int i = blockIdx.x * 256 + threadIdx.x;       // over 4096*256/8 = 131072
    int J = i >> 5;
    int kk = (i & 31) * 8;
    int mat = J >> 10, c = (J >> 8) & 3, jj = J & 255;
    const float* W = (mat == 0) ? Wq : (mat == 1) ? Wk : (mat == 2) ? Wv : Ws;
    const float* src = W + (size_t)c * 65536 + jj * 256 + kk;
    float4 v0 = ldf4(src);
    float4 v1 = ldf4(src + 4);
    ushort4 o0, o1;
    o0.x = f2bf(v0.x); o0.y = f2bf(v0.y); o0.z = f2bf(v0.z); o0.w = f2bf(v0.w);
    o1.x = f2bf(v1.x); o1.y = f2bf(v1.y); o1.z = f2bf(v1.z); o1.w = f2bf(v1.w);
    *reinterpret_cast<ushort4*>(WALL + (size_t)J * 256 + kk) = o0;
    *reinterpret_cast<ushort4*>(WALL + (size_t)J * 256 + kk + 4) = o1;
    if (kk == 0) {
        const float* b = (mat == 0) ? bq : (mat == 1) ? bk : (mat == 2) ? bv : bs;
        BALL[J] = b[c * 256 + jj];
    }
}

// ---------------------------------------------------------------- degree (int)
__global__ __launch_bounds__(256) void degi_kernel(const int* __restrict__ ei,
                                                   int* __restrict__ degi) {
    int e = blockIdx.x * 256 + threadIdx.x;
    if (e < N_EDGES) atomicAdd(&degi[ei[N_EDGES + e]], 1);
}

// ---------------------------------------------------------------- prefix sum (1 block)
__global__ __launch_bounds__(256) void scan_kernel(const int* __restrict__ degi,
                                                   int* __restrict__ rowptr,
                                                   int* __restrict__ cursor) {
    __shared__ int part[256];
    int t = threadIdx.x;
    int base = t * 40;
    int s = 0;
    for (int i = 0; i < 40; ++i) { int idx = base + i; if (idx < N_NODES) s += degi[idx]; }
    part[t] = s;
    __syncthreads();
    for (int off = 1; off < 256; off <<= 1) {
        int v = part[t];
        int u = (t >= off) ? part[t - off] : 0;
        __syncthreads();
        part[t] = v + u;
        __syncthreads();
    }
    int run = (t == 0) ? 0 : part[t - 1];
    for (int i = 0; i < 40; ++i) {
        int idx = base + i;
        if (idx < N_NODES) { rowptr[idx] = run; cursor[idx] = run; run += degi[idx]; }
    }
    if (t == 255) rowptr[N_NODES] = N_EDGES;
}

// ---------------------------------------------------------------- CSR scatter
__global__ __launch_bounds__(256) void scatter_kernel(const int* __restrict__ ei,
                                                      int* __restrict__ cursor,
                                                      int* __restrict__ csr_eid,
                                                      int* __restrict__ csr_src) {
    int e = blockIdx.x * 256 + threadIdx.x;
    if (e < N_EDGES) {
        int d = ei[N_EDGES + e];
        int p = atomicAdd(&cursor[d], 1);
        csr_eid[p] = e;
        csr_src[p] = ei[e];
    }
}

// ---------------------------------------------------------------- fused MFMA GEMM with LDS staging
// C[10000][4096] = xb[10000][256] . WALL[4096][256]^T (+BALL); epilogue splits to
// QKV[c][node][{q,k,v}][256] (bf16) and XCAT (f32).
__global__ __launch_bounds__(256) void gemm_tiled(
    const unsigned short* __restrict__ xb, const unsigned short* __restrict__ WALL,
    const float* __restrict__ BALL,
    unsigned short* __restrict__ QKV, float* __restrict__ XCAT)
{
    __shared__ __align__(16) unsigned short As[BM * BK];   // 8 KB, [row][chunk^((row>>1)&3)]
    __shared__ __align__(16) unsigned short Bs[BN * BK];   // 8 KB

    const int bid = blockIdx.x;
    const int f = (bid & 7) * CPX + (bid >> 3);   // XCD swizzle: bijective (2528 % 8 == 0)
    const int bm = (f >> 5) * BM, bn = (f & 31) * BN;

    const int tid = threadIdx.x, w = tid >> 6, lane = tid & 63;
    const int il = lane & 15, kg = lane >> 4;
    const int wr = w >> 1, wc = w & 1;

    const f4v zero = {0.f, 0.f, 0.f, 0.f};
    f4v acc[4][4];
    #pragma unroll
    for (int mi = 0; mi < 4; ++mi)
        #pragma unroll
        for (int ni = 0; ni < 4; ++ni) acc[mi][ni] = zero;

    for (int k0 = 0; k0 < DIM; k0 += BK) {
        #pragma unroll
        for (int t = 0; t < 2; ++t) {
            const int sidx = tid + t * 256;
            const int row = sidx >> 2, ch = sidx & 3;
            const int dc = ch ^ ((row >> 1) & 3);
            const int ldsbase = (t * 256 + w * 64) * 8;   // ushort idx; wave-uniform
            int ar = bm + row; ar = ar < N_NODES ? ar : N_NODES - 1;
            gload16(xb + (size_t)ar * DIM + k0 + dc * 8, As + ldsbase);
            gload16(WALL + (size_t)(bn + row) * DIM + k0 + dc * 8, Bs + ldsbase);
        }
        __syncthreads();   // compiler drains vmcnt before s_barrier

        s8v a[4], b[4];
        #pragma unroll
        for (int mi = 0; mi < 4; ++mi) {
            const int row = wr * 64 + mi * 16 + il;
            const int c2 = kg ^ ((row >> 1) & 3);
            a[mi] = *reinterpret_cast<const s8v*>(&As[row * 32 + c2 * 8]);
        }
        #pragma unroll
        for (int ni = 0; ni < 4; ++ni) {
            const int row = wc * 64 + ni * 16 + il;
            const int c2 = kg ^ ((row >> 1) & 3);
            b[ni] = *reinterpret_cast<const s8v*>(&Bs[row * 32 + c2 * 8]);
        }
        #pragma unroll
        for (int mi = 0; mi < 4; ++mi)
            #pragma unroll
            for (int ni = 0; ni < 4; ++ni)
                acc[mi][ni] = __builtin_amdgcn_mfma_f32_16x16x32_bf16(a[mi], b[ni], acc[mi][ni], 0, 0, 0);
        __syncthreads();
    }

    // Epilogue. D layout: col = lane&15, row(local) = (lane>>4)*4 + rr  [guide §3, m89/m91]
    #pragma unroll
    for (int ni = 0; ni < 4; ++ni) {
        const int col = bn + wc * 64 + ni * 16 + il;       // 0..4095
        const float bia = BALL[col];
        const int mat = col >> 10;
        const int cj = col & 1023;                          // c*256 + j
        const int cc = cj >> 8, jj = cj & 255;
        #pragma unroll
        for (int mi = 0; mi < 4; ++mi) {
            const int rbase = bm + wr * 64 + mi * 16 + kg * 4;
            #pragma unroll
            for (int rr = 0; rr < 4; ++rr) {
                const int r = rbase + rr;
                if (r < N_NODES) {
                    const float v = acc[mi][ni][rr] + bia;
                    if (mat == 3) XCAT[(size_t)r * 1024 + cj] = v;
                    else QKV[(((size_t)cc * N_NODES + r) * 3 + mat) * DIM + jj] = f2bf(v);
                }
            }
        }
    }
}

// ---------------------------------------------------------------- fused CSR edge pass
// block = one dst node, wave = one channel. Software-pipelined: iteration p+1's
// index/adj/gather loads issue before iteration p's compute -> gather latency
// hides under the shfl-reduce + tanh chain.
__global__ __launch_bounds__(256) void edge_fused(
    const int* __restrict__ rowptr, const int* __restrict__ csr_eid,
    const int* __restrict__ csr_src,
    const float* __restrict__ adj, const float* __restrict__ We,
    const unsigned short* __restrict__ QKV,
    float* __restrict__ XCAT, float* __restrict__ ALPHA)
{
    const int n = blockIdx.x;
    const int c = threadIdx.x >> 6, lane = threadIdx.x & 63, col = lane * 4;

    const size_t cbase = (size_t)c * N_NODES;
    const size_t nbase = (cbase + n) * 3 * DIM;
    float4 qd = ldbf4(QKV + nbase + col);
    float4 kd = ldbf4(QKV + nbase + DIM + col);
    float4 we = ldf4(&We[c * DIM + col]);

    float qdwe = qd.x * we.x + qd.y * we.y + qd.z * we.z + qd.w * we.w;
    #pragma unroll
    for (int off = 1; off <= 8; off <<= 1) qdwe += __shfl_xor(qdwe, off, 64);

    const float* adjc = adj + (size_t)c * N_EDGES;
    float4 acc = make_float4(0.f, 0.f, 0.f, 0.f);
    const int p0 = rowptr[n], p1 = rowptr[n + 1];

    if (p0 < p1) {
        // prologue: load edge p0
        int eid = csr_eid[p0];
        float av = adjc[eid];
        size_t sbase = (cbase + csr_src[p0]) * 3 * DIM;
        float4 qs = ldbf4(QKV + sbase + col);
        float4 ks = ldbf4(QKV + sbase + DIM + col);
        float4 vs = ldbf4(QKV + sbase + 2 * DIM + col);

        for (int p = p0; p < p1; ++p) {
            // ---- prefetch edge p+1 (clamped; independent of current compute)
            const int pn = (p + 1 < p1) ? p + 1 : p;
            const int eid2 = csr_eid[pn];
            const float av2 = adjc[eid2];
            const size_t sb2 = (cbase + csr_src[pn]) * 3 * DIM;
            const float4 qs2 = ldbf4(QKV + sb2 + col);
            const float4 ks2 = ldbf4(QKV + sb2 + DIM + col);
            const float4 vs2 = ldbf4(QKV + sb2 + 2 * DIM + col);

            // ---- compute edge p
            float d1 = qd.x*ks.x + qd.y*ks.y + qd.z*ks.z + qd.w*ks.w;
            float d2 = qs.x*kd.x + qs.y*kd.y + qs.z*kd.z + qs.w*kd.w;
            #pragma unroll
            for (int off = 1; off <= 8; off <<= 1) {
                d1 += __shfl_xor(d1, off, 64);
                d2 += __shfl_xor(d2, off, 64);
            }
            d1 += av * qdwe;
            float al = 0.5f * (fast_tanh(d1 * 0.125f) + fast_tanh(d2 * 0.125f));
            al += __shfl_xor(al, 16, 64);
            al += __shfl_xor(al, 32, 64);
            if (lane == 0) ALPHA[(size_t)eid * NCH + c] = al * 0.25f;
            acc.x += av * vs.x; acc.y += av * vs.y;
            acc.z += av * vs.z; acc.w += av * vs.w;

            // ---- rotate
            eid = eid2; av = av2; qs = qs2; ks = ks2; vs = vs2;
        }
    }
    float inv = 1.0f / fmaxf((float)(p1 - p0), 1.0f);
    float* xc = &XCAT[(size_t)n * (NCH * DIM) + c * DIM + col];
    float4 xv = ldf4(xc);
    xv.x += acc.x * we.x * inv; xv.y += acc.y * we.y * inv;
    xv.z += acc.z * we.z * inv; xv.w += acc.w * we.w * inv;
    *reinterpret_cast<float4*>(xc) = xv;
}

// ---------------------------------------------------------------- node MLP (1024->8 elu ->256 tanh)
__global__ __launch_bounds__(256) void node_final(
    const float* __restrict__ XCAT,
    const float* __restrict__ W1, const float* __restrict__ b1,
    const float* __restrict__ W2, const float* __restrict__ b2,
    float* __restrict__ out)
{
    int n    = (blockIdx.x * 256 + threadIdx.x) >> 6;
    int lane = threadIdx.x & 63;
    const float* xr = XCAT + (size_t)n * (NCH * DIM);
    float4 xv[4];
    #pragma unroll
    for (int t = 0; t < 4; ++t) xv[t] = ldf4(&xr[t * 256 + lane * 4]);
    float h[HIDD];
    #pragma unroll
    for (int j = 0; j < HIDD; ++j) {
        const float* wr = W1 + j * (NCH * DIM);
        float p = 0.f;
        #pragma unroll
        for (int t = 0; t < 4; ++t) {
            float4 wv = ldf4(&wr[t * 256 + lane * 4]);
            p += xv[t].x*wv.x + xv[t].y*wv.y + xv[t].z*wv.z + xv[t].w*wv.w;
        }
        #pragma unroll
        for (int off = 1; off < 64; off <<= 1) p += __shfl_xor(p, off, 64);
        h[j] = fast_elu(p + b1[j]);
    }
    float rr[4];
    #pragma unroll
    for (int i = 0; i < 4; ++i) {
        int colj = lane * 4 + i;
        float z = b2[colj];
        #pragma unroll
        for (int j = 0; j < HIDD; ++j) z += h[j] * W2[colj * HIDD + j];
        rr[i] = fast_tanh(z);
    }
    float4 r; r.x = rr[0]; r.y = rr[1]; r.z = rr[2]; r.w = rr[3];
    *reinterpret_cast<float4*>(&out[n * DIM + lane * 4]) = r;
}

// ---------------------------------------------------------------- edge MLP (8->8->8->4)
__global__ __launch_bounds__(256) void edge_mlp(
    const float* __restrict__ ALPHA, const float* __restrict__ adj,
    const float* __restrict__ W1, const float* __restrict__ b1,
    const float* __restrict__ W2, const float* __restrict__ b2,
    const float* __restrict__ W3, const float* __restrict__ b3,
    float* __restrict__ out)
{
    int e = blockIdx.x * 256 + threadIdx.x;
    if (e >= N_EDGES) return;
    float in[8];
    #pragma unroll
    for (int c = 0; c < NCH; ++c) in[c] = ALPHA[(size_t)e * NCH + c];
    #pragma unroll
    for (int c = 0; c < NCH; ++c) in[4 + c] = adj[(size_t)c * N_EDGES + e];
    float h1[8], h2[8];
    #pragma unroll
    for (int j = 0; j < 8; ++j) {
        float z = b1[j];
        #pragma unroll
        for (int i = 0; i < 8; ++i) z += W1[j*8 + i] * in[i];
        h1[j] = fast_elu(z);
    }
    #pragma unroll
    for (int j = 0; j < 8; ++j) {
        float z = b2[j];
        #pragma unroll
        for (int i = 0; i < 8; ++i) z += W2[j*8 + i] * h1[i];
        h2[j] = fast_elu(z);
    }
    #pragma unroll
    for (int o = 0; o < 4; ++o) {
        float z = b3[o];
        #pragma unroll
        for (int j = 0; j < 8; ++j) z += W3[o*8 + j] * h2[j];
        out[(size_t)o * N_EDGES + e] = z;
    }
}

// ---------------------------------------------------------------- launch
extern "C" void kernel_launch(void* const* d_in, const int* in_sizes, int n_in,
                              void* d_out, int out_size, void* d_ws, size_t ws_size,
                              hipStream_t stream) {
    const float* x    = (const float*)d_in[0];
    const int*   ei   = (const int*)  d_in[1];
    const float* adj  = (const float*)d_in[2];
    const float* Wq   = (const float*)d_in[4];
    const float* bq   = (const float*)d_in[5];
    const float* Wk   = (const float*)d_in[6];
    const float* bk   = (const float*)d_in[7];
    const float* Wv   = (const float*)d_in[8];
    const float* bv   = (const float*)d_in[9];
    const float* We   = (const float*)d_in[10];
    const float* Wsk  = (const float*)d_in[11];
    const float* bsk  = (const float*)d_in[12];
    const float* Wmc1 = (const float*)d_in[13];
    const float* bmc1 = (const float*)d_in[14];
    const float* Wmc2 = (const float*)d_in[15];
    const float* bmc2 = (const float*)d_in[16];
    const float* Wm1  = (const float*)d_in[17];
    const float* bm1  = (const float*)d_in[18];
    const float* Wm2  = (const float*)d_in[19];
    const float* bm2  = (const float*)d_in[20];
    const float* Wm3  = (const float*)d_in[21];
    const float* bm3  = (const float*)d_in[22];

    // ---- workspace layout (~113 MB total)
    char* w = (char*)d_ws;
    unsigned short* xb   = (unsigned short*)w; w += (size_t)N_NODES * DIM * 2;        // 5.12 MB
    unsigned short* WALL = (unsigned short*)w; w += (size_t)4096 * DIM * 2;           // 2.10 MB
    float*          BALL = (float*)w;          w += (size_t)4096 * 4;                 // 16 KB
    unsigned short* QKV  = (unsigned short*)w; w += (size_t)NCH * N_NODES * 3 * DIM * 2; // 61.44 MB
    float* XCAT  = (float*)w; w += (size_t)N_NODES * NCH * DIM * 4;                   // 40.96 MB
    float* ALPHA = (float*)w; w += (size_t)N_EDGES * NCH * 4;                         // 1.60 MB
    int* degi    = (int*)w; w += N_NODES * 4;
    int* rowptr  = (int*)w; w += (N_NODES + 1) * 4;
    int* cursor  = (int*)w; w += N_NODES * 4;
    int* csr_eid = (int*)w; w += N_EDGES * 4;
    int* csr_src = (int*)w; w += N_EDGES * 4;

    float* xout   = (float*)d_out;
    float* mlpout = xout + (size_t)N_NODES * DIM;

    // ---- bf16 conversions / weight packing
    cvt_bf16<<<(N_NODES * DIM / 8 + 255) / 256, 256, 0, stream>>>(x, xb, N_NODES * DIM / 8);
    pack_w<<<512, 256, 0, stream>>>(Wq, Wk, Wv, Wsk, bq, bk, bv, bsk, WALL, BALL);

    // ---- CSR build
    hipMemsetAsync(degi, 0, N_NODES * sizeof(int), stream);
    degi_kernel<<<(N_EDGES + 255) / 256, 256, 0, stream>>>(ei, degi);
    scan_kernel<<<1, 256, 0, stream>>>(degi, rowptr, cursor);
    scatter_kernel<<<(N_EDGES + 255) / 256, 256, 0, stream>>>(ei, cursor, csr_eid, csr_src);

    // ---- all 16 GEMMs as one fused LDS-tiled MFMA GEMM
    gemm_tiled<<<NWG, 256, 0, stream>>>(xb, WALL, BALL, QKV, XCAT);

    // ---- fused edge pass: all channels, one launch
    edge_fused<<<N_NODES, 256, 0, stream>>>(rowptr, csr_eid, csr_src, adj, We,
                                            QKV, XCAT, ALPHA);

    node_final<<<N_NODES / 4, 256, 0, stream>>>(XCAT, Wmc1, bmc1, Wmc2, bmc2, xout);
    edge_mlp<<<(N_EDGES + 255) / 256, 256, 0, stream>>>(ALPHA, adj, Wm1, bm1,
                                                        Wm2, bm2, Wm3, bm3, mlpout);
}